// Round 1
// baseline (579.008 us; speedup 1.0000x reference)
//
#include <hip/hip_runtime.h>

// ---------------------------------------------------------------------------
// Algebraic collapse of the whole block:
//   h = GN(x) = s_c * x + t_c            (per-batch per-channel affine)
//   y = [h ; 1]  (257 x HW)
//   qkv rows: o = head*12 + j, j in [0,4)=q, [4,8)=k, [8,12)=v; bias folded
//             as column 256 of the augmented weight rows W'.
//   scores[b,h,d,e] = 0.5 * Wq'_h  (y y^T)  Wk'_h^T      -- Gram' = y y^T
//   P = softmax over heads axis
//   attn[c=h*4+d, n] = sum_e P[h,d,e] v[h,e,n] = M_b y,  M_b[c,:] = P-mix of Wv'
//   final = out_w @ attn + out_b + x = (out_w @ M_b) y + out_b + x
//         = G_b @ x + g_b + x           (fold y back to raw x)
// Gram' itself is an affine function of the RAW Gram S = [x;1][x;1]^T, and GN
// stats (group mean / unbiased var) read off S's diagonal + last column.
// => exactly TWO passes over x: one syrk (k1), one 256x256 GEMM (k6).
// ---------------------------------------------------------------------------

constexpr int kB = 4;
constexpr int kC = 256;
constexpr int kHW = 16384;
constexpr int kHeads = 64;
constexpr int kNG = 32;
constexpr int kCPG = 8;
constexpr int kCP1 = 257;
constexpr int kSS = kCP1 * kCP1;
constexpr float kEPS = 1e-5f;
constexpr int kNSplit = 16;

// workspace layout (float offsets)
constexpr size_t oS     = 0;                                  // raw Gram S: B x 257 x 257 (upper tri + col 256)
constexpr size_t oGp    = oS + (size_t)kB * kSS;              // folded Gram': B x 257 x 257
constexpr size_t oSc    = oGp + (size_t)kB * kSS;             // s_c: B x 256
constexpr size_t oTc    = oSc + (size_t)kB * kC;              // t_c: B x 256
constexpr size_t oScore = oTc + (size_t)kB * kC;              // scores: B x 64 x 16
constexpr size_t oP     = oScore + (size_t)kB * kHeads * 16;  // softmax(P)
constexpr size_t oM     = oP + (size_t)kB * kHeads * 16;      // M: B x 256 x 257 (unused slot kept for clarity)
constexpr size_t oGm    = oM + (size_t)kB * kC * kCP1;        // G: B x 256 x 256
constexpr size_t oGv    = oGm + (size_t)kB * kC * kC;         // g: B x 256

// ---------------------------------------------------------------------------
// K1: raw Gram syrk. S[b,i,j] = sum_n x[b,i,n] x[b,j,n] (upper-triangle tiles)
//     plus row sums into S[b,i,256] from diagonal tiles.
// grid (10 triangle tiles, kNSplit n-splits, B), 256 thr, 64x64 tile, 4x4/thr.
// ---------------------------------------------------------------------------
__global__ __launch_bounds__(256) void k1_syrk(const float* __restrict__ x,
                                               float* __restrict__ S) {
  const int l = blockIdx.x;
  int ti, tj;
  if (l < 4)      { ti = 0; tj = l; }
  else if (l < 7) { ti = 1; tj = l - 3; }
  else if (l < 9) { ti = 2; tj = l - 5; }
  else            { ti = 3; tj = 3; }
  const int b = blockIdx.z;
  const int n0 = blockIdx.y * (kHW / kNSplit);
  const float* xb = x + (size_t)b * kC * kHW;
  const bool diag = (ti == tj);

  __shared__ float At[32][68];
  __shared__ float Bt[32][68];

  float acc[16];
#pragma unroll
  for (int i = 0; i < 16; ++i) acc[i] = 0.f;
  float rsum = 0.f;

  const int tid = threadIdx.x;
  const int i0 = (tid & 15) * 4;
  const int j0 = (tid >> 4) * 4;

  for (int nc = 0; nc < kHW / kNSplit; nc += 32) {
    const int nb = n0 + nc;
    int idx = tid;
#pragma unroll
    for (int r = 0; r < 2; ++r) {
      const int row = idx >> 3;
      const int c4 = (idx & 7) * 4;
      float4 va = *(const float4*)(xb + (size_t)(ti * 64 + row) * kHW + nb + c4);
      At[c4 + 0][row] = va.x; At[c4 + 1][row] = va.y;
      At[c4 + 2][row] = va.z; At[c4 + 3][row] = va.w;
      if (!diag) {
        float4 vb = *(const float4*)(xb + (size_t)(tj * 64 + row) * kHW + nb + c4);
        Bt[c4 + 0][row] = vb.x; Bt[c4 + 1][row] = vb.y;
        Bt[c4 + 2][row] = vb.z; Bt[c4 + 3][row] = vb.w;
      }
      idx += 256;
    }
    __syncthreads();
    float (*Bp)[68] = diag ? At : Bt;
#pragma unroll
    for (int kk = 0; kk < 32; ++kk) {
      float4 a  = *(const float4*)&At[kk][i0];
      float4 bb = *(const float4*)&Bp[kk][j0];
      acc[0]  += a.x * bb.x; acc[1]  += a.x * bb.y; acc[2]  += a.x * bb.z; acc[3]  += a.x * bb.w;
      acc[4]  += a.y * bb.x; acc[5]  += a.y * bb.y; acc[6]  += a.y * bb.z; acc[7]  += a.y * bb.w;
      acc[8]  += a.z * bb.x; acc[9]  += a.z * bb.y; acc[10] += a.z * bb.z; acc[11] += a.z * bb.w;
      acc[12] += a.w * bb.x; acc[13] += a.w * bb.y; acc[14] += a.w * bb.z; acc[15] += a.w * bb.w;
    }
    if (diag && tid < 64) {
      float rs = 0.f;
#pragma unroll
      for (int kk = 0; kk < 32; ++kk) rs += At[kk][tid];
      rsum += rs;
    }
    __syncthreads();
  }
  float* Sb = S + (size_t)b * kSS;
#pragma unroll
  for (int r = 0; r < 4; ++r)
#pragma unroll
    for (int cc = 0; cc < 4; ++cc)
      atomicAdd(&Sb[(size_t)(ti * 64 + i0 + r) * kCP1 + tj * 64 + j0 + cc], acc[r * 4 + cc]);
  if (diag && tid < 64)
    atomicAdd(&Sb[(size_t)(ti * 64 + tid) * kCP1 + 256], rsum);
}

// ---------------------------------------------------------------------------
// K2a: GN stats from S diag + row-sum column -> per-channel affine (s_c, t_c).
// grid (B), 256 thr.
// ---------------------------------------------------------------------------
__global__ __launch_bounds__(256) void k2a_stats(const float* __restrict__ S,
                                                 const float* __restrict__ gw,
                                                 const float* __restrict__ gb,
                                                 float* __restrict__ sArr,
                                                 float* __restrict__ tArr) {
  const int b = blockIdx.x;
  const float* Sb = S + (size_t)b * kSS;
  __shared__ float sx[kC], sdg[kC], meanv[kNG], invv[kNG];
  const int c = threadIdx.x;
  sx[c]  = Sb[(size_t)c * kCP1 + 256];
  sdg[c] = Sb[(size_t)c * kCP1 + c];
  __syncthreads();
  if (c < kNG) {
    float sum = 0.f, ssq = 0.f;
    for (int k = 0; k < kCPG; ++k) { sum += sx[c * kCPG + k]; ssq += sdg[c * kCPG + k]; }
    const float n = (float)(kCPG * kHW);
    const float mean = sum / n;
    const float var = (ssq - n * mean * mean) / (n - 1.0f);  // ddof=1 (unbiased)
    meanv[c] = mean;
    invv[c] = rsqrtf(var + kEPS);
  }
  __syncthreads();
  const int g = c / kCPG;
  const float s = gw[c] * invv[g];
  sArr[b * kC + c] = s;
  tArr[b * kC + c] = gb[c] - meanv[g] * s;
}

// ---------------------------------------------------------------------------
// K2: fold raw Gram -> normalized+augmented Gram'. grid (257, B), 256 thr.
// ---------------------------------------------------------------------------
__global__ __launch_bounds__(256) void k2_fold(const float* __restrict__ S,
                                               const float* __restrict__ sArr,
                                               const float* __restrict__ tArr,
                                               float* __restrict__ Gp) {
  const int b = blockIdx.y;
  const int c = blockIdx.x;  // 0..256
  const float* Sb = S + (size_t)b * kSS;
  float* Gb = Gp + (size_t)b * kSS;
  const float HWf = (float)kHW;
  __shared__ float sh_s[kC], sh_t[kC];
  sh_s[threadIdx.x] = sArr[b * kC + threadIdx.x];
  sh_t[threadIdx.x] = tArr[b * kC + threadIdx.x];
  __syncthreads();
  const float s_c = (c < kC) ? sh_s[c] : 0.f;
  const float t_c = (c < kC) ? sh_t[c] : 0.f;
  const float Sx_c = (c < kC) ? Sb[(size_t)c * kCP1 + 256] : 0.f;
  for (int cp = threadIdx.x; cp < kCP1; cp += 256) {
    float val;
    if (c < kC && cp < kC) {
      const float Scc = (cp >= c) ? Sb[(size_t)c * kCP1 + cp] : Sb[(size_t)cp * kCP1 + c];
      const float Sx_p = Sb[(size_t)cp * kCP1 + 256];
      val = s_c * sh_s[cp] * Scc + s_c * sh_t[cp] * Sx_c + t_c * sh_s[cp] * Sx_p + t_c * sh_t[cp] * HWf;
    } else if (c < kC) {          // cp == 256
      val = s_c * Sx_c + t_c * HWf;
    } else if (cp < kC) {         // c == 256
      val = sh_s[cp] * Sb[(size_t)cp * kCP1 + 256] + sh_t[cp] * HWf;
    } else {
      val = HWf;
    }
    Gb[(size_t)c * kCP1 + cp] = val;
  }
}

// ---------------------------------------------------------------------------
// K3: scores[b,h,d,e] = 0.5 * Wq'_h Gram' Wk'_h^T.  grid (64 heads, B), 256 thr.
// ---------------------------------------------------------------------------
__global__ __launch_bounds__(256) void k3_scores(const float* __restrict__ Gp,
                                                 const float* __restrict__ qkv_w,
                                                 const float* __restrict__ qkv_b,
                                                 float* __restrict__ score) {
  const int h = blockIdx.x, b = blockIdx.y;
  const float* Gb = Gp + (size_t)b * kSS;
  __shared__ float Wq[4][kCP1], Wk[4][kCP1], Aq[4][kCP1];
  for (int idx = threadIdx.x; idx < 4 * kCP1; idx += 256) {
    const int d = idx / kCP1, cp = idx - d * kCP1;
    Wq[d][cp] = (cp < kC) ? qkv_w[(size_t)(h * 12 + d) * kC + cp] : qkv_b[h * 12 + d];
    Wk[d][cp] = (cp < kC) ? qkv_w[(size_t)(h * 12 + 4 + d) * kC + cp] : qkv_b[h * 12 + 4 + d];
  }
  __syncthreads();
  for (int idx = threadIdx.x; idx < 4 * kCP1; idx += 256) {
    const int d = idx / kCP1, cp = idx - d * kCP1;
    float s = 0.f;
    for (int c = 0; c < kCP1; ++c) s += Wq[d][c] * Gb[(size_t)c * kCP1 + cp];
    Aq[d][cp] = s;
  }
  __syncthreads();
  if (threadIdx.x < 16) {
    const int d = threadIdx.x >> 2, e = threadIdx.x & 3;
    float s = 0.f;
    for (int c = 0; c < kCP1; ++c) s += Aq[d][c] * Wk[e][c];
    score[((size_t)(b * kHeads) + h) * 16 + threadIdx.x] = 0.5f * s;
  }
}

// ---------------------------------------------------------------------------
// K4: softmax over the HEADS axis. grid (16 de-pairs, B), 64 thr (one/head).
// ---------------------------------------------------------------------------
__global__ void k4_softmax(const float* __restrict__ score, float* __restrict__ P) {
  const int de = blockIdx.x;
  const int b = blockIdx.y;
  const int h = threadIdx.x;  // 0..63
  const float v = score[((size_t)(b * kHeads) + h) * 16 + de];
  float m = v;
#pragma unroll
  for (int off = 32; off; off >>= 1) m = fmaxf(m, __shfl_xor(m, off));
  const float e = expf(v - m);
  float ssum = e;
#pragma unroll
  for (int off = 32; off; off >>= 1) ssum += __shfl_xor(ssum, off);
  P[((size_t)(b * kHeads) + h) * 16 + de] = e / ssum;
}

// ---------------------------------------------------------------------------
// K5a: M[b, c=h*4+d, cp] = sum_e P[b,h,d,e] * Wv'[h,e,cp]. grid (256, B).
// ---------------------------------------------------------------------------
__global__ __launch_bounds__(256) void k5a_M(const float* __restrict__ P,
                                             const float* __restrict__ qkv_w,
                                             const float* __restrict__ qkv_b,
                                             float* __restrict__ M) {
  const int b = blockIdx.y;
  const int cidx = blockIdx.x;
  const int h = cidx >> 2, d = cidx & 3;
  const float p0 = P[((size_t)(b * kHeads) + h) * 16 + d * 4 + 0];
  const float p1 = P[((size_t)(b * kHeads) + h) * 16 + d * 4 + 1];
  const float p2 = P[((size_t)(b * kHeads) + h) * 16 + d * 4 + 2];
  const float p3 = P[((size_t)(b * kHeads) + h) * 16 + d * 4 + 3];
  for (int cp = threadIdx.x; cp < kCP1; cp += 256) {
    float a;
    if (cp < kC) {
      a = p0 * qkv_w[(size_t)(h * 12 + 8 + 0) * kC + cp] +
          p1 * qkv_w[(size_t)(h * 12 + 8 + 1) * kC + cp] +
          p2 * qkv_w[(size_t)(h * 12 + 8 + 2) * kC + cp] +
          p3 * qkv_w[(size_t)(h * 12 + 8 + 3) * kC + cp];
    } else {
      a = p0 * qkv_b[h * 12 + 8 + 0] + p1 * qkv_b[h * 12 + 8 + 1] +
          p2 * qkv_b[h * 12 + 8 + 2] + p3 * qkv_b[h * 12 + 8 + 3];
    }
    M[((size_t)b * kC + cidx) * kCP1 + cp] = a;
  }
}

// ---------------------------------------------------------------------------
// K5b: F = out_w @ M, then fold to G (x-space) and g (constant). grid (256, B).
// ---------------------------------------------------------------------------
__global__ __launch_bounds__(256) void k5b_F(const float* __restrict__ M,
                                             const float* __restrict__ out_w,
                                             const float* __restrict__ out_b,
                                             const float* __restrict__ sArr,
                                             const float* __restrict__ tArr,
                                             float* __restrict__ Gmat,
                                             float* __restrict__ gvec) {
  const int b = blockIdx.y, o = blockIdx.x;
  __shared__ float w_sh[kC];
  __shared__ float gpart[256];
  w_sh[threadIdx.x] = out_w[(size_t)o * kC + threadIdx.x];
  __syncthreads();
  float gp = 0.f;
  for (int cp = threadIdx.x; cp < kCP1; cp += 256) {
    float f = 0.f;
    for (int c = 0; c < kC; ++c) f += w_sh[c] * M[((size_t)b * kC + c) * kCP1 + cp];
    if (cp < kC) {
      Gmat[((size_t)b * kC + o) * kC + cp] = f * sArr[b * kC + cp];
      gp += f * tArr[b * kC + cp];
    } else {
      gp += f;  // F[o, 256] (bias column)
    }
  }
  gpart[threadIdx.x] = gp;
  __syncthreads();
  for (int s2 = 128; s2; s2 >>= 1) {
    if (threadIdx.x < s2) gpart[threadIdx.x] += gpart[threadIdx.x + s2];
    __syncthreads();
  }
  if (threadIdx.x == 0) gvec[b * kC + o] = gpart[0] + out_b[o];
}

// ---------------------------------------------------------------------------
// K6: out[b,o,n] = sum_c G[b,o,c] x[b,c,n] + g[b,o] + x[b,o,n]
// grid (HW/64, C/64, B), 256 thr, 64x64 tile, 4x4 per thread, K chunked by 32.
// ---------------------------------------------------------------------------
__global__ __launch_bounds__(256) void k6_final(const float* __restrict__ x,
                                                const float* __restrict__ Gmat,
                                                const float* __restrict__ gvec,
                                                float* __restrict__ out) {
  const int nt = blockIdx.x, ot = blockIdx.y, b = blockIdx.z;
  const float* xb = x + (size_t)b * kC * kHW;
  __shared__ float Gt[32][68];
  __shared__ float Xs[32][68];
  float acc[16];
#pragma unroll
  for (int i = 0; i < 16; ++i) acc[i] = 0.f;
  const int tid = threadIdx.x;
  const int o0 = (tid >> 4) * 4;
  const int n0 = (tid & 15) * 4;

  for (int cb = 0; cb < kC; cb += 32) {
    int idx = tid;
#pragma unroll
    for (int r = 0; r < 2; ++r) {
      const int oo = idx >> 3;
      const int c4 = (idx & 7) * 4;
      float4 v = *(const float4*)&Gmat[((size_t)b * kC + ot * 64 + oo) * kC + cb + c4];
      Gt[c4 + 0][oo] = v.x; Gt[c4 + 1][oo] = v.y;
      Gt[c4 + 2][oo] = v.z; Gt[c4 + 3][oo] = v.w;
      idx += 256;
    }
    idx = tid;
#pragma unroll
    for (int r = 0; r < 2; ++r) {
      const int cc = idx >> 4;
      const int nn4 = (idx & 15) * 4;
      float4 v = *(const float4*)&xb[(size_t)(cb + cc) * kHW + nt * 64 + nn4];
      *(float4*)&Xs[cc][nn4] = v;
      idx += 256;
    }
    __syncthreads();
#pragma unroll
    for (int kk = 0; kk < 32; ++kk) {
      float4 a  = *(const float4*)&Gt[kk][o0];
      float4 bb = *(const float4*)&Xs[kk][n0];
      acc[0]  += a.x * bb.x; acc[1]  += a.x * bb.y; acc[2]  += a.x * bb.z; acc[3]  += a.x * bb.w;
      acc[4]  += a.y * bb.x; acc[5]  += a.y * bb.y; acc[6]  += a.y * bb.z; acc[7]  += a.y * bb.w;
      acc[8]  += a.z * bb.x; acc[9]  += a.z * bb.y; acc[10] += a.z * bb.z; acc[11] += a.z * bb.w;
      acc[12] += a.w * bb.x; acc[13] += a.w * bb.y; acc[14] += a.w * bb.z; acc[15] += a.w * bb.w;
    }
    __syncthreads();
  }
#pragma unroll
  for (int r = 0; r < 4; ++r) {
    const int o = ot * 64 + o0 + r;
    const float gvv = gvec[b * kC + o];
    float4 sk = *(const float4*)&xb[(size_t)o * kHW + nt * 64 + n0];
    float4 res;
    res.x = acc[r * 4 + 0] + gvv + sk.x;
    res.y = acc[r * 4 + 1] + gvv + sk.y;
    res.z = acc[r * 4 + 2] + gvv + sk.z;
    res.w = acc[r * 4 + 3] + gvv + sk.w;
    *(float4*)&out[((size_t)b * kC + o) * kHW + nt * 64 + n0] = res;
  }
}

extern "C" void kernel_launch(void* const* d_in, const int* in_sizes, int n_in,
                              void* d_out, int out_size, void* d_ws, size_t ws_size,
                              hipStream_t stream) {
  const float* x    = (const float*)d_in[0];
  const float* gnw  = (const float*)d_in[1];
  const float* gnb  = (const float*)d_in[2];
  const float* qkvw = (const float*)d_in[3];
  const float* qkvb = (const float*)d_in[4];
  const float* outw = (const float*)d_in[5];
  const float* outb = (const float*)d_in[6];
  float* out = (float*)d_out;
  float* ws = (float*)d_ws;

  float* S     = ws + oS;
  float* Gp    = ws + oGp;
  float* sArr  = ws + oSc;
  float* tArr  = ws + oTc;
  float* score = ws + oScore;
  float* P     = ws + oP;
  float* M     = ws + oM;
  float* Gm    = ws + oGm;
  float* gv    = ws + oGv;

  hipMemsetAsync(S, 0, (size_t)kB * kSS * sizeof(float), stream);
  k1_syrk<<<dim3(10, kNSplit, kB), 256, 0, stream>>>(x, S);
  k2a_stats<<<kB, 256, 0, stream>>>(S, gnw, gnb, sArr, tArr);
  k2_fold<<<dim3(kCP1, kB), 256, 0, stream>>>(S, sArr, tArr, Gp);
  k3_scores<<<dim3(kHeads, kB), 256, 0, stream>>>(Gp, qkvw, qkvb, score);
  k4_softmax<<<dim3(16, kB), 64, 0, stream>>>(score, P);
  k5a_M<<<dim3(kC, kB), 256, 0, stream>>>(P, qkvw, qkvb, M);
  k5b_F<<<dim3(kC, kB), 256, 0, stream>>>(M, outw, outb, sArr, tArr, Gm, gv);
  k6_final<<<dim3(kHW / 64, kC / 64, kB), 256, 0, stream>>>(x, Gm, gv, out);
}

// Round 2
// 288.894 us; speedup vs baseline: 2.0042x; 2.0042x over previous
//
#include <hip/hip_runtime.h>

// ---------------------------------------------------------------------------
// Algebraic collapse (see round 1) + fp16 MFMA for the two big GEMMs:
//   k0: x (fp32) -> xT (fp16, [b][n][c]) tiled transpose + exact fp32 row sums
//   k1: S = X X^T via mfma_f32_16x16x32_f16, inline fp32->fp16 staging,
//       XOR-swizzled LDS, 128x128 tiles x 16 K-splits -> Spart, then reduce
//   k2a/k2_fold: GN affine + fold raw Gram -> normalized augmented Gram'
//   k3/k4/k5a/k5b: scores / softmax-over-heads / P-mix / G (fp16) + g
//   k6: out = G(fp16) @ X(fp16 from xT) + g + x(skip, fp32)  via MFMA
// ---------------------------------------------------------------------------

constexpr int kB = 4;
constexpr int kC = 256;
constexpr int kHW = 16384;
constexpr int kHeads = 64;
constexpr int kNG = 32;
constexpr int kCPG = 8;
constexpr int kCP1 = 257;
constexpr int kSS = kCP1 * kCP1;
constexpr float kEPS = 1e-5f;
constexpr int kNSplit = 16;      // syrk K-splits

typedef __attribute__((ext_vector_type(8))) _Float16 f16x8;
typedef __attribute__((ext_vector_type(4))) float f32x4;

union V8 { f16x8 v; uint4 u; _Float16 h[8]; };

// workspace layout (float-unit offsets)
constexpr size_t oXT    = 0;                                   // fp16 xT: B*HW*C halves = 8.39M floats
constexpr size_t oSpart = oXT + (size_t)kB * kHW * kC / 2;     // 3*4*16*128*128 floats
constexpr size_t oS     = oSpart + (size_t)3 * kB * kNSplit * 128 * 128;
constexpr size_t oGp    = oS + (size_t)kB * kSS;
constexpr size_t oM     = oGp + (size_t)kB * kSS;
constexpr size_t oSums  = oM + (size_t)kB * kC * kCP1;
constexpr size_t oSc    = oSums + (size_t)kB * kC;
constexpr size_t oTc    = oSc + (size_t)kB * kC;
constexpr size_t oScore = oTc + (size_t)kB * kC;
constexpr size_t oP     = oScore + (size_t)kB * kHeads * 16;
constexpr size_t oGv    = oP + (size_t)kB * kHeads * 16;
constexpr size_t oGmH   = oGv + (size_t)kB * kC;               // fp16 G: B*256*256 halves
// total ~12.47M floats ~ 49.9 MB

// ---------------------------------------------------------------------------
// K0: tiled transpose x -> xT (fp16) + exact fp32 row sums.
// grid (HW/64, C/64, B), 256 thr, 64x64 tile.
// ---------------------------------------------------------------------------
__global__ __launch_bounds__(256) void k0_tr(const float* __restrict__ x,
                                             _Float16* __restrict__ xT,
                                             float* __restrict__ sums) {
  const int nt = blockIdx.x, ct = blockIdx.y, b = blockIdx.z;
  __shared__ float T[64][65];
  __shared__ float psum[64][4];
  const float* xb = x + ((size_t)b * kC + ct * 64) * kHW + nt * 64;
  const int tid = threadIdx.x;

#pragma unroll
  for (int rep = 0; rep < 4; ++rep) {
    const int r = rep * 16 + (tid >> 4);          // c-local
    const int c4 = (tid & 15) * 4;                // n-local
    float4 v = *(const float4*)(xb + (size_t)r * kHW + c4);
    T[r][c4 + 0] = v.x; T[r][c4 + 1] = v.y; T[r][c4 + 2] = v.z; T[r][c4 + 3] = v.w;
  }
  __syncthreads();
  {
    const int q = tid >> 6, r = tid & 63;
    float s = 0.f;
#pragma unroll
    for (int i = 0; i < 16; ++i) s += T[r][q * 16 + i];
    psum[r][q] = s;
  }
  __syncthreads();
  if (tid < 64) {
    float s = psum[tid][0] + psum[tid][1] + psum[tid][2] + psum[tid][3];
    atomicAdd(&sums[b * kC + ct * 64 + tid], s);
  }
  // transpose out: thread -> n-row nl = tid>>2, c-group cgrp = tid&3 (16 c each)
  const int nl = tid >> 2, cgrp = tid & 3;
  V8 lo, hi;
#pragma unroll
  for (int i = 0; i < 8; ++i)  lo.h[i] = (_Float16)T[cgrp * 16 + i][nl];
#pragma unroll
  for (int i = 0; i < 8; ++i)  hi.h[i] = (_Float16)T[cgrp * 16 + 8 + i][nl];
  _Float16* dst = xT + ((size_t)b * kHW + nt * 64 + nl) * kC + ct * 64 + cgrp * 16;
  *(uint4*)dst = lo.u;
  *(uint4*)(dst + 8) = hi.u;
}

// ---------------------------------------------------------------------------
// K1: MFMA syrk. Tiles (0,0),(0,1),(1,1) of 128x128; K-split 16 x 1024.
// grid (3*16, B), 256 thr (4 waves, each 64x64 sub-tile).
// LDS: XI/XJ 128 rows x 64 fp16, row=128B=8 granules, swizzle g^(r&7).
// ---------------------------------------------------------------------------
__global__ __launch_bounds__(256) void k1_syrk(const float* __restrict__ x,
                                               float* __restrict__ Spart) {
  const int tt = blockIdx.x >> 4;   // 0:(0,0) 1:(0,1) 2:(1,1)
  const int sp = blockIdx.x & 15;
  const int b = blockIdx.y;
  const int ti = (tt == 2) ? 1 : 0;
  const int tj = (tt == 0) ? 0 : 1;
  const bool diag = (ti == tj);
  const float* xb = x + (size_t)b * kC * kHW;
  const int n0 = sp * (kHW / kNSplit);   // 1024 per split

  __shared__ __align__(16) _Float16 XI[128 * 64];
  __shared__ __align__(16) _Float16 XJ[128 * 64];

  const int tid = threadIdx.x;
  const int wave = tid >> 6, lane = tid & 63;
  const int wi = wave >> 1, wj = wave & 1;
  const int lrow = lane & 15, lgq = lane >> 4;

  f32x4 acc[16];
#pragma unroll
  for (int i = 0; i < 16; ++i) acc[i] = (f32x4){0.f, 0.f, 0.f, 0.f};

  for (int ch = 0; ch < 16; ++ch) {
    const int nb = n0 + ch * 64;
#pragma unroll
    for (int rep = 0; rep < 4; ++rep) {
      const int gi = tid + rep * 256;
      const int r = gi >> 3, g = gi & 7;
      const size_t boff = (size_t)r * 128 + (((unsigned)(g ^ (r & 7))) << 4);
      {
        const float* src = xb + (size_t)(ti * 128 + r) * kHW + nb + g * 8;
        float4 a0 = *(const float4*)src;
        float4 a1 = *(const float4*)(src + 4);
        V8 w;
        w.h[0] = (_Float16)a0.x; w.h[1] = (_Float16)a0.y; w.h[2] = (_Float16)a0.z; w.h[3] = (_Float16)a0.w;
        w.h[4] = (_Float16)a1.x; w.h[5] = (_Float16)a1.y; w.h[6] = (_Float16)a1.z; w.h[7] = (_Float16)a1.w;
        *(uint4*)((char*)XI + boff) = w.u;
      }
      if (!diag) {
        const float* src = xb + (size_t)(tj * 128 + r) * kHW + nb + g * 8;
        float4 a0 = *(const float4*)src;
        float4 a1 = *(const float4*)(src + 4);
        V8 w;
        w.h[0] = (_Float16)a0.x; w.h[1] = (_Float16)a0.y; w.h[2] = (_Float16)a0.z; w.h[3] = (_Float16)a0.w;
        w.h[4] = (_Float16)a1.x; w.h[5] = (_Float16)a1.y; w.h[6] = (_Float16)a1.z; w.h[7] = (_Float16)a1.w;
        *(uint4*)((char*)XJ + boff) = w.u;
      }
    }
    __syncthreads();
    const _Float16* XB = diag ? XI : XJ;
#pragma unroll
    for (int sub = 0; sub < 2; ++sub) {
      const int gq = sub * 4 + lgq;
      f16x8 afr[4], bfr[4];
#pragma unroll
      for (int ia = 0; ia < 4; ++ia) {
        const int r = wi * 64 + ia * 16 + lrow;
        afr[ia] = *(const f16x8*)((const char*)XI + (size_t)r * 128 + (((unsigned)(gq ^ (r & 7))) << 4));
      }
#pragma unroll
      for (int jb = 0; jb < 4; ++jb) {
        const int r = wj * 64 + jb * 16 + lrow;
        bfr[jb] = *(const f16x8*)((const char*)XB + (size_t)r * 128 + (((unsigned)(gq ^ (r & 7))) << 4));
      }
#pragma unroll
      for (int ia = 0; ia < 4; ++ia)
#pragma unroll
        for (int jb = 0; jb < 4; ++jb)
          acc[ia * 4 + jb] = __builtin_amdgcn_mfma_f32_16x16x32_f16(afr[ia], bfr[jb], acc[ia * 4 + jb], 0, 0, 0);
    }
    __syncthreads();
  }
  float* P = Spart + (((size_t)tt * kB + b) * kNSplit + sp) * 16384;
#pragma unroll
  for (int ia = 0; ia < 4; ++ia)
#pragma unroll
    for (int jb = 0; jb < 4; ++jb)
#pragma unroll
      for (int reg = 0; reg < 4; ++reg) {
        const int i = wi * 64 + ia * 16 + lgq * 4 + reg;
        const int j = wj * 64 + jb * 16 + lrow;
        P[(size_t)i * 128 + j] = acc[ia * 4 + jb][reg];
      }
}

// ---------------------------------------------------------------------------
// K1r: reduce split partials -> S (upper-triangle tiles). grid (192), 256 thr.
// ---------------------------------------------------------------------------
__global__ __launch_bounds__(256) void k1r_reduce(const float* __restrict__ Spart,
                                                  float* __restrict__ S) {
  const int blk = blockIdx.x;
  const int tile12 = blk >> 4;          // 0..11
  const int part = blk & 15;
  const int tt = tile12 >> 2, b = tile12 & 3;
  const int rti = (tt == 2) ? 1 : 0;
  const int rtj = (tt == 0) ? 0 : 1;
  const int e0 = part * 1024 + threadIdx.x * 4;
  float4 s = {0.f, 0.f, 0.f, 0.f};
  const float* base = Spart + ((size_t)tt * kB + b) * kNSplit * 16384 + e0;
  for (int sp = 0; sp < kNSplit; ++sp) {
    float4 v = *(const float4*)(base + (size_t)sp * 16384);
    s.x += v.x; s.y += v.y; s.z += v.z; s.w += v.w;
  }
  const int i = e0 >> 7, j = e0 & 127;
  float* dst = S + (size_t)b * kSS + (size_t)(rti * 128 + i) * kCP1 + rtj * 128 + j;
  dst[0] = s.x; dst[1] = s.y; dst[2] = s.z; dst[3] = s.w;
}

// ---------------------------------------------------------------------------
// K2a: GN stats from S diag (fp16-gram, ok) + exact sums -> affine (s_c, t_c).
// ---------------------------------------------------------------------------
__global__ __launch_bounds__(256) void k2a_stats(const float* __restrict__ S,
                                                 const float* __restrict__ sums,
                                                 const float* __restrict__ gw,
                                                 const float* __restrict__ gb,
                                                 float* __restrict__ sArr,
                                                 float* __restrict__ tArr) {
  const int b = blockIdx.x;
  const float* Sb = S + (size_t)b * kSS;
  __shared__ float sx[kC], sdg[kC], meanv[kNG], invv[kNG];
  const int c = threadIdx.x;
  sx[c]  = sums[b * kC + c];
  sdg[c] = Sb[(size_t)c * kCP1 + c];
  __syncthreads();
  if (c < kNG) {
    float sum = 0.f, ssq = 0.f;
    for (int k = 0; k < kCPG; ++k) { sum += sx[c * kCPG + k]; ssq += sdg[c * kCPG + k]; }
    const float n = (float)(kCPG * kHW);
    const float mean = sum / n;
    const float var = (ssq - n * mean * mean) / (n - 1.0f);  // ddof=1
    meanv[c] = mean;
    invv[c] = rsqrtf(var + kEPS);
  }
  __syncthreads();
  const int g = c / kCPG;
  const float s = gw[c] * invv[g];
  sArr[b * kC + c] = s;
  tArr[b * kC + c] = gb[c] - meanv[g] * s;
}

// ---------------------------------------------------------------------------
// K2: fold raw Gram -> normalized+augmented Gram'. grid (257, B), 256 thr.
// ---------------------------------------------------------------------------
__global__ __launch_bounds__(256) void k2_fold(const float* __restrict__ S,
                                               const float* __restrict__ sums,
                                               const float* __restrict__ sArr,
                                               const float* __restrict__ tArr,
                                               float* __restrict__ Gp) {
  const int b = blockIdx.y;
  const int c = blockIdx.x;  // 0..256
  const float* Sb = S + (size_t)b * kSS;
  float* Gb = Gp + (size_t)b * kSS;
  const float HWf = (float)kHW;
  __shared__ float sh_s[kC], sh_t[kC], sh_x[kC];
  sh_s[threadIdx.x] = sArr[b * kC + threadIdx.x];
  sh_t[threadIdx.x] = tArr[b * kC + threadIdx.x];
  sh_x[threadIdx.x] = sums[b * kC + threadIdx.x];
  __syncthreads();
  const float s_c = (c < kC) ? sh_s[c] : 0.f;
  const float t_c = (c < kC) ? sh_t[c] : 0.f;
  const float Sx_c = (c < kC) ? sh_x[c] : 0.f;
  for (int cp = threadIdx.x; cp < kCP1; cp += 256) {
    float val;
    if (c < kC && cp < kC) {
      const float Scc = (cp >= c) ? Sb[(size_t)c * kCP1 + cp] : Sb[(size_t)cp * kCP1 + c];
      val = s_c * sh_s[cp] * Scc + s_c * sh_t[cp] * Sx_c + t_c * sh_s[cp] * sh_x[cp] + t_c * sh_t[cp] * HWf;
    } else if (c < kC) {          // cp == 256
      val = s_c * Sx_c + t_c * HWf;
    } else if (cp < kC) {         // c == 256
      val = sh_s[cp] * sh_x[cp] + sh_t[cp] * HWf;
    } else {
      val = HWf;
    }
    Gb[(size_t)c * kCP1 + cp] = val;
  }
}

// ---------------------------------------------------------------------------
// K3: scores = 0.5 * Wq'_h Gram' Wk'_h^T.  grid (64 heads, B), 256 thr.
// ---------------------------------------------------------------------------
__global__ __launch_bounds__(256) void k3_scores(const float* __restrict__ Gp,
                                                 const float* __restrict__ qkv_w,
                                                 const float* __restrict__ qkv_b,
                                                 float* __restrict__ score) {
  const int h = blockIdx.x, b = blockIdx.y;
  const float* Gb = Gp + (size_t)b * kSS;
  __shared__ float Wq[4][kCP1], Wk[4][kCP1], Aq[4][kCP1];
  for (int idx = threadIdx.x; idx < 4 * kCP1; idx += 256) {
    const int d = idx / kCP1, cp = idx - d * kCP1;
    Wq[d][cp] = (cp < kC) ? qkv_w[(size_t)(h * 12 + d) * kC + cp] : qkv_b[h * 12 + d];
    Wk[d][cp] = (cp < kC) ? qkv_w[(size_t)(h * 12 + 4 + d) * kC + cp] : qkv_b[h * 12 + 4 + d];
  }
  __syncthreads();
  for (int idx = threadIdx.x; idx < 4 * kCP1; idx += 256) {
    const int d = idx / kCP1, cp = idx - d * kCP1;
    float s = 0.f;
    for (int c = 0; c < kCP1; ++c) s += Wq[d][c] * Gb[(size_t)c * kCP1 + cp];
    Aq[d][cp] = s;
  }
  __syncthreads();
  if (threadIdx.x < 16) {
    const int d = threadIdx.x >> 2, e = threadIdx.x & 3;
    float s = 0.f;
    for (int c = 0; c < kCP1; ++c) s += Aq[d][c] * Wk[e][c];
    score[((size_t)(b * kHeads) + h) * 16 + threadIdx.x] = 0.5f * s;
  }
}

// ---------------------------------------------------------------------------
// K4: softmax over HEADS. grid (16, B), 64 thr.
// ---------------------------------------------------------------------------
__global__ void k4_softmax(const float* __restrict__ score, float* __restrict__ P) {
  const int de = blockIdx.x;
  const int b = blockIdx.y;
  const int h = threadIdx.x;
  const float v = score[((size_t)(b * kHeads) + h) * 16 + de];
  float m = v;
#pragma unroll
  for (int off = 32; off; off >>= 1) m = fmaxf(m, __shfl_xor(m, off));
  const float e = expf(v - m);
  float ssum = e;
#pragma unroll
  for (int off = 32; off; off >>= 1) ssum += __shfl_xor(ssum, off);
  P[((size_t)(b * kHeads) + h) * 16 + de] = e / ssum;
}

// ---------------------------------------------------------------------------
// K5a: M = P-mix of Wv'. grid (256, B).
// ---------------------------------------------------------------------------
__global__ __launch_bounds__(256) void k5a_M(const float* __restrict__ P,
                                             const float* __restrict__ qkv_w,
                                             const float* __restrict__ qkv_b,
                                             float* __restrict__ M) {
  const int b = blockIdx.y;
  const int cidx = blockIdx.x;
  const int h = cidx >> 2, d = cidx & 3;
  const float p0 = P[((size_t)(b * kHeads) + h) * 16 + d * 4 + 0];
  const float p1 = P[((size_t)(b * kHeads) + h) * 16 + d * 4 + 1];
  const float p2 = P[((size_t)(b * kHeads) + h) * 16 + d * 4 + 2];
  const float p3 = P[((size_t)(b * kHeads) + h) * 16 + d * 4 + 3];
  for (int cp = threadIdx.x; cp < kCP1; cp += 256) {
    float a;
    if (cp < kC) {
      a = p0 * qkv_w[(size_t)(h * 12 + 8 + 0) * kC + cp] +
          p1 * qkv_w[(size_t)(h * 12 + 8 + 1) * kC + cp] +
          p2 * qkv_w[(size_t)(h * 12 + 8 + 2) * kC + cp] +
          p3 * qkv_w[(size_t)(h * 12 + 8 + 3) * kC + cp];
    } else {
      a = p0 * qkv_b[h * 12 + 8 + 0] + p1 * qkv_b[h * 12 + 8 + 1] +
          p2 * qkv_b[h * 12 + 8 + 2] + p3 * qkv_b[h * 12 + 8 + 3];
    }
    M[((size_t)b * kC + cidx) * kCP1 + cp] = a;
  }
}

// ---------------------------------------------------------------------------
// K5b: F = out_w @ M; G (fp16, x-space) and g (fp32). grid (256, B).
// ---------------------------------------------------------------------------
__global__ __launch_bounds__(256) void k5b_F(const float* __restrict__ M,
                                             const float* __restrict__ out_w,
                                             const float* __restrict__ out_b,
                                             const float* __restrict__ sArr,
                                             const float* __restrict__ tArr,
                                             _Float16* __restrict__ GmH,
                                             float* __restrict__ gvec) {
  const int b = blockIdx.y, o = blockIdx.x;
  __shared__ float w_sh[kC];
  __shared__ float gpart[256];
  w_sh[threadIdx.x] = out_w[(size_t)o * kC + threadIdx.x];
  __syncthreads();
  float gp = 0.f;
  for (int cp = threadIdx.x; cp < kCP1; cp += 256) {
    float f = 0.f;
    for (int c = 0; c < kC; ++c) f += w_sh[c] * M[((size_t)b * kC + c) * kCP1 + cp];
    if (cp < kC) {
      GmH[((size_t)b * kC + o) * kC + cp] = (_Float16)(f * sArr[b * kC + cp]);
      gp += f * tArr[b * kC + cp];
    } else {
      gp += f;
    }
  }
  gpart[threadIdx.x] = gp;
  __syncthreads();
  for (int s2 = 128; s2; s2 >>= 1) {
    if (threadIdx.x < s2) gpart[threadIdx.x] += gpart[threadIdx.x + s2];
    __syncthreads();
  }
  if (threadIdx.x == 0) gvec[b * kC + o] = gpart[0] + out_b[o];
}

// ---------------------------------------------------------------------------
// K6: out = G @ X + g + skip via MFMA. grid (HW/128, C/128, B), 256 thr.
// A = G rows (fp16), B = xT rows (n-major fp16). LDS swizzled as in k1.
// ---------------------------------------------------------------------------
__global__ __launch_bounds__(256) void k6_final(const _Float16* __restrict__ xT,
                                                const _Float16* __restrict__ GmH,
                                                const float* __restrict__ gvec,
                                                const float* __restrict__ x,
                                                float* __restrict__ out) {
  const int nt = blockIdx.x, ot = blockIdx.y, b = blockIdx.z;
  __shared__ __align__(16) _Float16 GT[128 * 64];
  __shared__ __align__(16) _Float16 XT[128 * 64];
  const int tid = threadIdx.x;
  const int wave = tid >> 6, lane = tid & 63;
  const int wo = wave >> 1, wn = wave & 1;
  const int lrow = lane & 15, lgq = lane >> 4;

  f32x4 acc[16];
#pragma unroll
  for (int i = 0; i < 16; ++i) acc[i] = (f32x4){0.f, 0.f, 0.f, 0.f};

  for (int cc = 0; cc < kC; cc += 64) {
#pragma unroll
    for (int rep = 0; rep < 4; ++rep) {
      const int gi = tid + rep * 256;
      const int r = gi >> 3, g = gi & 7;
      const size_t boff = (size_t)r * 128 + (((unsigned)(g ^ (r & 7))) << 4);
      uint4 gv = *(const uint4*)(GmH + ((size_t)(b * kC + ot * 128 + r)) * kC + cc + g * 8);
      *(uint4*)((char*)GT + boff) = gv;
      uint4 xv = *(const uint4*)(xT + ((size_t)b * kHW + nt * 128 + r) * kC + cc + g * 8);
      *(uint4*)((char*)XT + boff) = xv;
    }
    __syncthreads();
#pragma unroll
    for (int sub = 0; sub < 2; ++sub) {
      const int gq = sub * 4 + lgq;
      f16x8 afr[4], bfr[4];
#pragma unroll
      for (int ia = 0; ia < 4; ++ia) {
        const int r = wo * 64 + ia * 16 + lrow;
        afr[ia] = *(const f16x8*)((const char*)GT + (size_t)r * 128 + (((unsigned)(gq ^ (r & 7))) << 4));
      }
#pragma unroll
      for (int jb = 0; jb < 4; ++jb) {
        const int r = wn * 64 + jb * 16 + lrow;
        bfr[jb] = *(const f16x8*)((const char*)XT + (size_t)r * 128 + (((unsigned)(gq ^ (r & 7))) << 4));
      }
#pragma unroll
      for (int ia = 0; ia < 4; ++ia)
#pragma unroll
        for (int jb = 0; jb < 4; ++jb)
          acc[ia * 4 + jb] = __builtin_amdgcn_mfma_f32_16x16x32_f16(afr[ia], bfr[jb], acc[ia * 4 + jb], 0, 0, 0);
    }
    __syncthreads();
  }
#pragma unroll
  for (int ia = 0; ia < 4; ++ia)
#pragma unroll
    for (int reg = 0; reg < 4; ++reg) {
      const int o = ot * 128 + wo * 64 + ia * 16 + lgq * 4 + reg;
      const float gvv = gvec[b * kC + o];
#pragma unroll
      for (int jb = 0; jb < 4; ++jb) {
        const int n = nt * 128 + wn * 64 + jb * 16 + lrow;
        const size_t idx = ((size_t)b * kC + o) * kHW + n;
        out[idx] = acc[ia * 4 + jb][reg] + gvv + x[idx];
      }
    }
}

extern "C" void kernel_launch(void* const* d_in, const int* in_sizes, int n_in,
                              void* d_out, int out_size, void* d_ws, size_t ws_size,
                              hipStream_t stream) {
  const float* x    = (const float*)d_in[0];
  const float* gnw  = (const float*)d_in[1];
  const float* gnb  = (const float*)d_in[2];
  const float* qkvw = (const float*)d_in[3];
  const float* qkvb = (const float*)d_in[4];
  const float* outw = (const float*)d_in[5];
  const float* outb = (const float*)d_in[6];
  float* out = (float*)d_out;
  float* ws = (float*)d_ws;

  _Float16* xT   = (_Float16*)(ws + oXT);
  float* Spart   = ws + oSpart;
  float* S       = ws + oS;
  float* Gp      = ws + oGp;
  float* M       = ws + oM;
  float* sums    = ws + oSums;
  float* sArr    = ws + oSc;
  float* tArr    = ws + oTc;
  float* score   = ws + oScore;
  float* P       = ws + oP;
  float* gv      = ws + oGv;
  _Float16* GmH  = (_Float16*)(ws + oGmH);

  hipMemsetAsync(sums, 0, (size_t)kB * kC * sizeof(float), stream);
  k0_tr<<<dim3(kHW / 64, kC / 64, kB), 256, 0, stream>>>(x, xT, sums);
  k1_syrk<<<dim3(3 * kNSplit, kB), 256, 0, stream>>>(x, Spart);
  k1r_reduce<<<dim3(3 * kB * 16), 256, 0, stream>>>(Spart, S);
  k2a_stats<<<kB, 256, 0, stream>>>(S, sums, gnw, gnb, sArr, tArr);
  k2_fold<<<dim3(kCP1, kB), 256, 0, stream>>>(S, sums, sArr, tArr, Gp);
  k3_scores<<<dim3(kHeads, kB), 256, 0, stream>>>(Gp, qkvw, qkvb, score);
  k4_softmax<<<dim3(16, kB), 64, 0, stream>>>(score, P);
  k5a_M<<<dim3(kC, kB), 256, 0, stream>>>(P, qkvw, qkvb, M);
  k5b_F<<<dim3(kC, kB), 256, 0, stream>>>(M, outw, outb, sArr, tArr, GmH, gv);
  k6_final<<<dim3(kHW / 128, kC / 128, kB), 256, 0, stream>>>(xT, GmH, gv, x, out);
}

// Round 3
// 252.882 us; speedup vs baseline: 2.2896x; 1.1424x over previous
//
#include <hip/hip_runtime.h>

// ---------------------------------------------------------------------------
// Algebraic collapse + fp16 MFMA (rounds 1-2) + round-3: latency-bound fixes.
//   k0: x -> xT (fp16 [b][n][c]) + xH (fp16 [b][c][n]) + exact fp32 row sums
//   k1: S = X X^T via MFMA reading xH (fp16, 4x less HBM, no repack VALU)
//   k2a/k2_fold: GN affine + fold raw Gram -> augmented Gram' (row stride 260)
//   k3a: Aq = Wq' @ Gram'  -- LDS-tiled GEMM (was the 60us latency hole)
//   k3b: scores = 0.5 * Aq . Wk'  -- wave-reduced dot products
//   k4: softmax over heads; k5a: M = P-mix of Wv' (stride 260)
//   k5b: F = out_w @ M -- LDS-tiled GEMM -> G (fp16) + gvec (atomics)
//   k6: out = G @ X + (g + out_b) + skip via MFMA
// ---------------------------------------------------------------------------

constexpr int kB = 4;
constexpr int kC = 256;
constexpr int kHW = 16384;
constexpr int kHeads = 64;
constexpr int kNG = 32;
constexpr int kCPG = 8;
constexpr int kCP1 = 257;
constexpr int kSS = kCP1 * kCP1;
constexpr int kPS = 260;          // padded row stride for Gp / M (16B-aligned rows)
constexpr float kEPS = 1e-5f;
constexpr int kNSplit = 16;       // syrk K-splits

typedef __attribute__((ext_vector_type(8))) _Float16 f16x8;
typedef __attribute__((ext_vector_type(4))) _Float16 f16x4;
typedef __attribute__((ext_vector_type(4))) float f32x4;

union V8 { f16x8 v; uint4 u; _Float16 h[8]; };

// workspace layout (float-unit offsets)
constexpr size_t oXT    = 0;                                    // fp16 xT [b][n][c]
constexpr size_t oXH    = oXT + (size_t)kB * kHW * kC / 2;      // fp16 xH [b][c][n]
constexpr size_t oSpart = oXH + (size_t)kB * kHW * kC / 2;      // 3*B*16*128*128
constexpr size_t oS     = oSpart + (size_t)3 * kB * kNSplit * 128 * 128;
constexpr size_t oGp    = oS + (size_t)kB * kSS;                // B x 257 x 260
constexpr size_t oSums  = oGp + (size_t)kB * kCP1 * kPS;
constexpr size_t oGv    = oSums + (size_t)kB * kC;              // adjacent to sums (one memset)
constexpr size_t oSc    = oGv + (size_t)kB * kC;
constexpr size_t oTc    = oSc + (size_t)kB * kC;
constexpr size_t oScore = oTc + (size_t)kB * kC;
constexpr size_t oP     = oScore + (size_t)kB * kHeads * 16;
// overlays (lifetime-disjoint):
constexpr size_t oAq    = oSpart;                               // B x 256 x 257 (after k1r)
constexpr size_t oM     = oXH;                                  // B x 256 x 260 (after k1)
constexpr size_t oGmH   = oXH + (size_t)kB * kC * kPS;          // fp16 B x 256 x 256

// ---------------------------------------------------------------------------
// K0: tiled transpose x -> xT (fp16) + xH (fp16 same layout) + fp32 row sums.
// grid (HW/64, C/64, B), 256 thr.
// ---------------------------------------------------------------------------
__global__ __launch_bounds__(256) void k0_tr(const float* __restrict__ x,
                                             _Float16* __restrict__ xT,
                                             _Float16* __restrict__ xH,
                                             float* __restrict__ sums) {
  const int nt = blockIdx.x, ct = blockIdx.y, b = blockIdx.z;
  __shared__ float T[64][65];
  __shared__ float psum[64][4];
  const float* xb = x + ((size_t)b * kC + ct * 64) * kHW + nt * 64;
  _Float16* xhb = xH + ((size_t)b * kC + ct * 64) * kHW + nt * 64;
  const int tid = threadIdx.x;

#pragma unroll
  for (int rep = 0; rep < 4; ++rep) {
    const int r = rep * 16 + (tid >> 4);          // c-local
    const int c4 = (tid & 15) * 4;                // n-local
    float4 v = *(const float4*)(xb + (size_t)r * kHW + c4);
    T[r][c4 + 0] = v.x; T[r][c4 + 1] = v.y; T[r][c4 + 2] = v.z; T[r][c4 + 3] = v.w;
    f16x4 hv = {(_Float16)v.x, (_Float16)v.y, (_Float16)v.z, (_Float16)v.w};
    *(f16x4*)(xhb + (size_t)r * kHW + c4) = hv;   // 8B store
  }
  __syncthreads();
  {
    const int q = tid >> 6, r = tid & 63;
    float s = 0.f;
#pragma unroll
    for (int i = 0; i < 16; ++i) s += T[r][q * 16 + i];
    psum[r][q] = s;
  }
  __syncthreads();
  if (tid < 64) {
    float s = psum[tid][0] + psum[tid][1] + psum[tid][2] + psum[tid][3];
    atomicAdd(&sums[b * kC + ct * 64 + tid], s);
  }
  const int nl = tid >> 2, cgrp = tid & 3;
  V8 lo, hi;
#pragma unroll
  for (int i = 0; i < 8; ++i)  lo.h[i] = (_Float16)T[cgrp * 16 + i][nl];
#pragma unroll
  for (int i = 0; i < 8; ++i)  hi.h[i] = (_Float16)T[cgrp * 16 + 8 + i][nl];
  _Float16* dst = xT + ((size_t)b * kHW + nt * 64 + nl) * kC + ct * 64 + cgrp * 16;
  *(uint4*)dst = lo.u;
  *(uint4*)(dst + 8) = hi.u;
}

// ---------------------------------------------------------------------------
// K1: MFMA syrk reading xH (fp16). Tiles (0,0),(0,1),(1,1) of 128x128;
// K-split 16 x 1024. grid (48, B), 256 thr. LDS swizzle g^(r&7).
// ---------------------------------------------------------------------------
__global__ __launch_bounds__(256) void k1_syrk(const _Float16* __restrict__ xH,
                                               float* __restrict__ Spart) {
  const int tt = blockIdx.x >> 4;   // 0:(0,0) 1:(0,1) 2:(1,1)
  const int sp = blockIdx.x & 15;
  const int b = blockIdx.y;
  const int ti = (tt == 2) ? 1 : 0;
  const int tj = (tt == 0) ? 0 : 1;
  const bool diag = (ti == tj);
  const _Float16* xb = xH + (size_t)b * kC * kHW;
  const int n0 = sp * (kHW / kNSplit);   // 1024 per split

  __shared__ __align__(16) _Float16 XI[128 * 64];
  __shared__ __align__(16) _Float16 XJ[128 * 64];

  const int tid = threadIdx.x;
  const int wave = tid >> 6, lane = tid & 63;
  const int wi = wave >> 1, wj = wave & 1;
  const int lrow = lane & 15, lgq = lane >> 4;

  f32x4 acc[16];
#pragma unroll
  for (int i = 0; i < 16; ++i) acc[i] = (f32x4){0.f, 0.f, 0.f, 0.f};

  for (int ch = 0; ch < 16; ++ch) {
    const int nb = n0 + ch * 64;
#pragma unroll
    for (int rep = 0; rep < 4; ++rep) {
      const int gi = tid + rep * 256;
      const int r = gi >> 3, g = gi & 7;
      const size_t boff = (size_t)r * 128 + (((unsigned)(g ^ (r & 7))) << 4);
      uint4 va = *(const uint4*)(xb + (size_t)(ti * 128 + r) * kHW + nb + g * 8);
      *(uint4*)((char*)XI + boff) = va;
      if (!diag) {
        uint4 vb = *(const uint4*)(xb + (size_t)(tj * 128 + r) * kHW + nb + g * 8);
        *(uint4*)((char*)XJ + boff) = vb;
      }
    }
    __syncthreads();
    const _Float16* XB = diag ? XI : XJ;
#pragma unroll
    for (int sub = 0; sub < 2; ++sub) {
      const int gq = sub * 4 + lgq;
      f16x8 afr[4], bfr[4];
#pragma unroll
      for (int ia = 0; ia < 4; ++ia) {
        const int r = wi * 64 + ia * 16 + lrow;
        afr[ia] = *(const f16x8*)((const char*)XI + (size_t)r * 128 + (((unsigned)(gq ^ (r & 7))) << 4));
      }
#pragma unroll
      for (int jb = 0; jb < 4; ++jb) {
        const int r = wj * 64 + jb * 16 + lrow;
        bfr[jb] = *(const f16x8*)((const char*)XB + (size_t)r * 128 + (((unsigned)(gq ^ (r & 7))) << 4));
      }
#pragma unroll
      for (int ia = 0; ia < 4; ++ia)
#pragma unroll
        for (int jb = 0; jb < 4; ++jb)
          acc[ia * 4 + jb] = __builtin_amdgcn_mfma_f32_16x16x32_f16(afr[ia], bfr[jb], acc[ia * 4 + jb], 0, 0, 0);
    }
    __syncthreads();
  }
  float* P = Spart + (((size_t)tt * kB + b) * kNSplit + sp) * 16384;
#pragma unroll
  for (int ia = 0; ia < 4; ++ia)
#pragma unroll
    for (int jb = 0; jb < 4; ++jb)
#pragma unroll
      for (int reg = 0; reg < 4; ++reg) {
        const int i = wi * 64 + ia * 16 + lgq * 4 + reg;
        const int j = wj * 64 + jb * 16 + lrow;
        P[(size_t)i * 128 + j] = acc[ia * 4 + jb][reg];
      }
}

// ---------------------------------------------------------------------------
// K1r: reduce split partials -> S. grid (192), 256 thr.
// ---------------------------------------------------------------------------
__global__ __launch_bounds__(256) void k1r_reduce(const float* __restrict__ Spart,
                                                  float* __restrict__ S) {
  const int blk = blockIdx.x;
  const int tile12 = blk >> 4;
  const int part = blk & 15;
  const int tt = tile12 >> 2, b = tile12 & 3;
  const int rti = (tt == 2) ? 1 : 0;
  const int rtj = (tt == 0) ? 0 : 1;
  const int e0 = part * 1024 + threadIdx.x * 4;
  float4 s = {0.f, 0.f, 0.f, 0.f};
  const float* base = Spart + ((size_t)tt * kB + b) * kNSplit * 16384 + e0;
  for (int sp = 0; sp < kNSplit; ++sp) {
    float4 v = *(const float4*)(base + (size_t)sp * 16384);
    s.x += v.x; s.y += v.y; s.z += v.z; s.w += v.w;
  }
  const int i = e0 >> 7, j = e0 & 127;
  float* dst = S + (size_t)b * kSS + (size_t)(rti * 128 + i) * kCP1 + rtj * 128 + j;
  dst[0] = s.x; dst[1] = s.y; dst[2] = s.z; dst[3] = s.w;
}

// ---------------------------------------------------------------------------
// K2a: GN stats -> per-channel affine (s_c, t_c). grid (B), 256 thr.
// ---------------------------------------------------------------------------
__global__ __launch_bounds__(256) void k2a_stats(const float* __restrict__ S,
                                                 const float* __restrict__ sums,
                                                 const float* __restrict__ gw,
                                                 const float* __restrict__ gb,
                                                 float* __restrict__ sArr,
                                                 float* __restrict__ tArr) {
  const int b = blockIdx.x;
  const float* Sb = S + (size_t)b * kSS;
  __shared__ float sx[kC], sdg[kC], meanv[kNG], invv[kNG];
  const int c = threadIdx.x;
  sx[c]  = sums[b * kC + c];
  sdg[c] = Sb[(size_t)c * kCP1 + c];
  __syncthreads();
  if (c < kNG) {
    float sum = 0.f, ssq = 0.f;
    for (int k = 0; k < kCPG; ++k) { sum += sx[c * kCPG + k]; ssq += sdg[c * kCPG + k]; }
    const float n = (float)(kCPG * kHW);
    const float mean = sum / n;
    const float var = (ssq - n * mean * mean) / (n - 1.0f);  // ddof=1
    meanv[c] = mean;
    invv[c] = rsqrtf(var + kEPS);
  }
  __syncthreads();
  const int g = c / kCPG;
  const float s = gw[c] * invv[g];
  sArr[b * kC + c] = s;
  tArr[b * kC + c] = gb[c] - meanv[g] * s;
}

// ---------------------------------------------------------------------------
// K2: fold raw Gram -> normalized+augmented Gram' (row stride kPS=260).
// grid (257, B), 256 thr.
// ---------------------------------------------------------------------------
__global__ __launch_bounds__(256) void k2_fold(const float* __restrict__ S,
                                               const float* __restrict__ sums,
                                               const float* __restrict__ sArr,
                                               const float* __restrict__ tArr,
                                               float* __restrict__ Gp) {
  const int b = blockIdx.y;
  const int c = blockIdx.x;  // 0..256
  const float* Sb = S + (size_t)b * kSS;
  float* Gb = Gp + (size_t)b * kCP1 * kPS;
  const float HWf = (float)kHW;
  __shared__ float sh_s[kC], sh_t[kC], sh_x[kC];
  sh_s[threadIdx.x] = sArr[b * kC + threadIdx.x];
  sh_t[threadIdx.x] = tArr[b * kC + threadIdx.x];
  sh_x[threadIdx.x] = sums[b * kC + threadIdx.x];
  __syncthreads();
  const float s_c = (c < kC) ? sh_s[c] : 0.f;
  const float t_c = (c < kC) ? sh_t[c] : 0.f;
  const float Sx_c = (c < kC) ? sh_x[c] : 0.f;
  for (int cp = threadIdx.x; cp < kCP1; cp += 256) {
    float val;
    if (c < kC && cp < kC) {
      const float Scc = (cp >= c) ? Sb[(size_t)c * kCP1 + cp] : Sb[(size_t)cp * kCP1 + c];
      val = s_c * sh_s[cp] * Scc + s_c * sh_t[cp] * Sx_c + t_c * sh_s[cp] * sh_x[cp] + t_c * sh_t[cp] * HWf;
    } else if (c < kC) {
      val = s_c * Sx_c + t_c * HWf;
    } else if (cp < kC) {
      val = sh_s[cp] * sh_x[cp] + sh_t[cp] * HWf;
    } else {
      val = HWf;
    }
    Gb[(size_t)c * kPS + cp] = val;
  }
}

// ---------------------------------------------------------------------------
// K3a: Aq[b,m,cp] = sum_{c<=256} Wq'[m,c] * Gp[b,c,cp]. Tiled 64x64, K=256
// chunks of 32 + bias-row epilogue. grid (5 cp-tiles, 4 m-tiles, B), 256 thr.
// ---------------------------------------------------------------------------
__global__ __launch_bounds__(256) void k3a_aq(const float* __restrict__ Gp,
                                              const float* __restrict__ qkv_w,
                                              const float* __restrict__ qkv_b,
                                              float* __restrict__ Aq) {
  const int ct = blockIdx.x, mt = blockIdx.y, b = blockIdx.z;
  const float* Gb = Gp + (size_t)b * kCP1 * kPS;
  __shared__ float Wt[32][68];
  __shared__ float Gs[32][68];
  float acc[16];
#pragma unroll
  for (int i = 0; i < 16; ++i) acc[i] = 0.f;
  const int tid = threadIdx.x;
  const int i0 = (tid & 15) * 4;   // m-local
  const int j0 = (tid >> 4) * 4;   // cp-local
  const int cp0 = ct * 64;

  for (int cb = 0; cb < kC; cb += 32) {
    int idx = tid;
#pragma unroll
    for (int r = 0; r < 2; ++r) {
      const int m = idx >> 3;
      const int c4 = (idx & 7) * 4;
      const int mg = mt * 64 + m;
      const int row = 12 * (mg >> 2) + (mg & 3);
      float4 v = *(const float4*)(qkv_w + (size_t)row * kC + cb + c4);
      Wt[c4 + 0][m] = v.x; Wt[c4 + 1][m] = v.y; Wt[c4 + 2][m] = v.z; Wt[c4 + 3][m] = v.w;
      idx += 256;
    }
    idx = tid;
#pragma unroll
    for (int r = 0; r < 2; ++r) {
      const int cc = idx >> 4;
      const int n4 = (idx & 15) * 4;
      float4 v = {0.f, 0.f, 0.f, 0.f};
      if (cp0 + n4 < kCP1) v = *(const float4*)(Gb + (size_t)(cb + cc) * kPS + cp0 + n4);
      *(float4*)&Gs[cc][n4] = v;
      idx += 256;
    }
    __syncthreads();
#pragma unroll
    for (int kk = 0; kk < 32; ++kk) {
      float4 a = *(const float4*)&Wt[kk][i0];
      float4 g = *(const float4*)&Gs[kk][j0];
      acc[0]  += a.x * g.x; acc[1]  += a.x * g.y; acc[2]  += a.x * g.z; acc[3]  += a.x * g.w;
      acc[4]  += a.y * g.x; acc[5]  += a.y * g.y; acc[6]  += a.y * g.z; acc[7]  += a.y * g.w;
      acc[8]  += a.z * g.x; acc[9]  += a.z * g.y; acc[10] += a.z * g.z; acc[11] += a.z * g.w;
      acc[12] += a.w * g.x; acc[13] += a.w * g.y; acc[14] += a.w * g.z; acc[15] += a.w * g.w;
    }
    __syncthreads();
  }
#pragma unroll
  for (int mi = 0; mi < 4; ++mi) {
    const int mg = mt * 64 + i0 + mi;
    const float bias = qkv_b[12 * (mg >> 2) + (mg & 3)];
#pragma unroll
    for (int cj = 0; cj < 4; ++cj) {
      const int cp = cp0 + j0 + cj;
      if (cp < kCP1)
        Aq[((size_t)b * kC + mg) * kCP1 + cp] = acc[mi * 4 + cj] + bias * Gb[(size_t)256 * kPS + cp];
    }
  }
}

// ---------------------------------------------------------------------------
// K3b: scores[b,h,d,e] = 0.5 * sum_cp Aq[b,4h+d,cp] * Wk'[4h+e,cp].
// grid (64 heads, B), 256 thr = 4 waves x 4 pairs each, wave-reduce.
// ---------------------------------------------------------------------------
__global__ __launch_bounds__(256) void k3b_scores(const float* __restrict__ Aq,
                                                  const float* __restrict__ qkv_w,
                                                  const float* __restrict__ qkv_b,
                                                  float* __restrict__ score) {
  const int h = blockIdx.x, b = blockIdx.y;
  const int tid = threadIdx.x, wave = tid >> 6, lane = tid & 63;
#pragma unroll
  for (int p = wave; p < 16; p += 4) {
    const int d = p >> 2, e = p & 3;
    const float* aqr = Aq + ((size_t)b * kC + h * 4 + d) * kCP1;
    const int krow = h * 12 + 4 + e;
    float s = 0.f;
#pragma unroll
    for (int it = 0; it < 4; ++it) {
      const int cp = lane + it * 64;
      s += aqr[cp] * qkv_w[(size_t)krow * kC + cp];
    }
    if (lane == 0) s += aqr[256] * qkv_b[krow];
#pragma unroll
    for (int off = 32; off; off >>= 1) s += __shfl_xor(s, off);
    if (lane == 0) score[((size_t)(b * kHeads) + h) * 16 + p] = 0.5f * s;
  }
}

// ---------------------------------------------------------------------------
// K4: softmax over HEADS. grid (16, B), 64 thr.
// ---------------------------------------------------------------------------
__global__ void k4_softmax(const float* __restrict__ score, float* __restrict__ P) {
  const int de = blockIdx.x;
  const int b = blockIdx.y;
  const int h = threadIdx.x;
  const float v = score[((size_t)(b * kHeads) + h) * 16 + de];
  float m = v;
#pragma unroll
  for (int off = 32; off; off >>= 1) m = fmaxf(m, __shfl_xor(m, off));
  const float e = expf(v - m);
  float ssum = e;
#pragma unroll
  for (int off = 32; off; off >>= 1) ssum += __shfl_xor(ssum, off);
  P[((size_t)(b * kHeads) + h) * 16 + de] = e / ssum;
}

// ---------------------------------------------------------------------------
// K5a: M = P-mix of Wv' (row stride kPS). grid (256, B).
// ---------------------------------------------------------------------------
__global__ __launch_bounds__(256) void k5a_M(const float* __restrict__ P,
                                             const float* __restrict__ qkv_w,
                                             const float* __restrict__ qkv_b,
                                             float* __restrict__ M) {
  const int b = blockIdx.y;
  const int cidx = blockIdx.x;
  const int h = cidx >> 2, d = cidx & 3;
  const float p0 = P[((size_t)(b * kHeads) + h) * 16 + d * 4 + 0];
  const float p1 = P[((size_t)(b * kHeads) + h) * 16 + d * 4 + 1];
  const float p2 = P[((size_t)(b * kHeads) + h) * 16 + d * 4 + 2];
  const float p3 = P[((size_t)(b * kHeads) + h) * 16 + d * 4 + 3];
  for (int cp = threadIdx.x; cp < kCP1; cp += 256) {
    float a;
    if (cp < kC) {
      a = p0 * qkv_w[(size_t)(h * 12 + 8 + 0) * kC + cp] +
          p1 * qkv_w[(size_t)(h * 12 + 8 + 1) * kC + cp] +
          p2 * qkv_w[(size_t)(h * 12 + 8 + 2) * kC + cp] +
          p3 * qkv_w[(size_t)(h * 12 + 8 + 3) * kC + cp];
    } else {
      a = p0 * qkv_b[h * 12 + 8 + 0] + p1 * qkv_b[h * 12 + 8 + 1] +
          p2 * qkv_b[h * 12 + 8 + 2] + p3 * qkv_b[h * 12 + 8 + 3];
    }
    M[((size_t)b * kC + cidx) * kPS + cp] = a;
  }
}

// ---------------------------------------------------------------------------
// K5b: F = out_w @ M (tiled 64x64, K=256); emit G fp16 (x-space) + gvec
// partial sums via atomics. grid (5 cp-tiles, 4 o-tiles, B), 256 thr.
// ---------------------------------------------------------------------------
__global__ __launch_bounds__(256) void k5b_gemm(const float* __restrict__ M,
                                                const float* __restrict__ out_w,
                                                const float* __restrict__ sArr,
                                                const float* __restrict__ tArr,
                                                _Float16* __restrict__ GmH,
                                                float* __restrict__ gvec) {
  const int ct = blockIdx.x, ot = blockIdx.y, b = blockIdx.z;
  const float* Mb = M + (size_t)b * kC * kPS;
  __shared__ float Wt[32][68];
  __shared__ float Gs[32][68];
  __shared__ float gred[64][17];
  float acc[16];
#pragma unroll
  for (int i = 0; i < 16; ++i) acc[i] = 0.f;
  const int tid = threadIdx.x;
  const int i0 = (tid & 15) * 4;   // o-local
  const int j0 = (tid >> 4) * 4;   // cp-local
  const int cp0 = ct * 64;

  for (int cb = 0; cb < kC; cb += 32) {
    int idx = tid;
#pragma unroll
    for (int r = 0; r < 2; ++r) {
      const int m = idx >> 3;
      const int c4 = (idx & 7) * 4;
      float4 v = *(const float4*)(out_w + (size_t)(ot * 64 + m) * kC + cb + c4);
      Wt[c4 + 0][m] = v.x; Wt[c4 + 1][m] = v.y; Wt[c4 + 2][m] = v.z; Wt[c4 + 3][m] = v.w;
      idx += 256;
    }
    idx = tid;
#pragma unroll
    for (int r = 0; r < 2; ++r) {
      const int cc = idx >> 4;
      const int n4 = (idx & 15) * 4;
      float4 v = {0.f, 0.f, 0.f, 0.f};
      if (cp0 + n4 < kCP1) v = *(const float4*)(Mb + (size_t)(cb + cc) * kPS + cp0 + n4);
      *(float4*)&Gs[cc][n4] = v;
      idx += 256;
    }
    __syncthreads();
#pragma unroll
    for (int kk = 0; kk < 32; ++kk) {
      float4 a = *(const float4*)&Wt[kk][i0];
      float4 g = *(const float4*)&Gs[kk][j0];
      acc[0]  += a.x * g.x; acc[1]  += a.x * g.y; acc[2]  += a.x * g.z; acc[3]  += a.x * g.w;
      acc[4]  += a.y * g.x; acc[5]  += a.y * g.y; acc[6]  += a.y * g.z; acc[7]  += a.y * g.w;
      acc[8]  += a.z * g.x; acc[9]  += a.z * g.y; acc[10] += a.z * g.z; acc[11] += a.z * g.w;
      acc[12] += a.w * g.x; acc[13] += a.w * g.y; acc[14] += a.w * g.z; acc[15] += a.w * g.w;
    }
    __syncthreads();
  }
  float gpart[4] = {0.f, 0.f, 0.f, 0.f};
#pragma unroll
  for (int mi = 0; mi < 4; ++mi) {
    const int o = ot * 64 + i0 + mi;
#pragma unroll
    for (int cj = 0; cj < 4; ++cj) {
      const int cp = cp0 + j0 + cj;
      const float f = acc[mi * 4 + cj];
      if (cp < kC) {
        GmH[((size_t)b * kC + o) * kC + cp] = (_Float16)(f * sArr[b * kC + cp]);
        gpart[mi] += f * tArr[b * kC + cp];
      } else if (cp == kC) {
        gpart[mi] += f;   // bias column of F
      }
    }
  }
#pragma unroll
  for (int mi = 0; mi < 4; ++mi) gred[i0 + mi][tid >> 4] = gpart[mi];
  __syncthreads();
  if (tid < 64) {
    float s = 0.f;
#pragma unroll
    for (int k = 0; k < 16; ++k) s += gred[tid][k];
    atomicAdd(&gvec[b * kC + ot * 64 + tid], s);
  }
}

// ---------------------------------------------------------------------------
// K6: out = G @ X + (g + out_b) + skip via MFMA. grid (HW/128, C/128, B).
// ---------------------------------------------------------------------------
__global__ __launch_bounds__(256) void k6_final(const _Float16* __restrict__ xT,
                                                const _Float16* __restrict__ GmH,
                                                const float* __restrict__ gvec,
                                                const float* __restrict__ out_b,
                                                const float* __restrict__ x,
                                                float* __restrict__ out) {
  const int nt = blockIdx.x, ot = blockIdx.y, b = blockIdx.z;
  __shared__ __align__(16) _Float16 GT[128 * 64];
  __shared__ __align__(16) _Float16 XT[128 * 64];
  const int tid = threadIdx.x;
  const int wave = tid >> 6, lane = tid & 63;
  const int wo = wave >> 1, wn = wave & 1;
  const int lrow = lane & 15, lgq = lane >> 4;

  f32x4 acc[16];
#pragma unroll
  for (int i = 0; i < 16; ++i) acc[i] = (f32x4){0.f, 0.f, 0.f, 0.f};

  for (int cc = 0; cc < kC; cc += 64) {
#pragma unroll
    for (int rep = 0; rep < 4; ++rep) {
      const int gi = tid + rep * 256;
      const int r = gi >> 3, g = gi & 7;
      const size_t boff = (size_t)r * 128 + (((unsigned)(g ^ (r & 7))) << 4);
      uint4 gv = *(const uint4*)(GmH + ((size_t)(b * kC + ot * 128 + r)) * kC + cc + g * 8);
      *(uint4*)((char*)GT + boff) = gv;
      uint4 xv = *(const uint4*)(xT + ((size_t)b * kHW + nt * 128 + r) * kC + cc + g * 8);
      *(uint4*)((char*)XT + boff) = xv;
    }
    __syncthreads();
#pragma unroll
    for (int sub = 0; sub < 2; ++sub) {
      const int gq = sub * 4 + lgq;
      f16x8 afr[4], bfr[4];
#pragma unroll
      for (int ia = 0; ia < 4; ++ia) {
        const int r = wo * 64 + ia * 16 + lrow;
        afr[ia] = *(const f16x8*)((const char*)GT + (size_t)r * 128 + (((unsigned)(gq ^ (r & 7))) << 4));
      }
#pragma unroll
      for (int jb = 0; jb < 4; ++jb) {
        const int r = wn * 64 + jb * 16 + lrow;
        bfr[jb] = *(const f16x8*)((const char*)XT + (size_t)r * 128 + (((unsigned)(gq ^ (r & 7))) << 4));
      }
#pragma unroll
      for (int ia = 0; ia < 4; ++ia)
#pragma unroll
        for (int jb = 0; jb < 4; ++jb)
          acc[ia * 4 + jb] = __builtin_amdgcn_mfma_f32_16x16x32_f16(afr[ia], bfr[jb], acc[ia * 4 + jb], 0, 0, 0);
    }
    __syncthreads();
  }
#pragma unroll
  for (int ia = 0; ia < 4; ++ia)
#pragma unroll
    for (int reg = 0; reg < 4; ++reg) {
      const int o = ot * 128 + wo * 64 + ia * 16 + lgq * 4 + reg;
      const float gvv = gvec[b * kC + o] + out_b[o];
#pragma unroll
      for (int jb = 0; jb < 4; ++jb) {
        const int n = nt * 128 + wn * 64 + jb * 16 + lrow;
        const size_t idx = ((size_t)b * kC + o) * kHW + n;
        out[idx] = acc[ia * 4 + jb][reg] + gvv + x[idx];
      }
    }
}

extern "C" void kernel_launch(void* const* d_in, const int* in_sizes, int n_in,
                              void* d_out, int out_size, void* d_ws, size_t ws_size,
                              hipStream_t stream) {
  const float* x    = (const float*)d_in[0];
  const float* gnw  = (const float*)d_in[1];
  const float* gnb  = (const float*)d_in[2];
  const float* qkvw = (const float*)d_in[3];
  const float* qkvb = (const float*)d_in[4];
  const float* outw = (const float*)d_in[5];
  const float* outb = (const float*)d_in[6];
  float* out = (float*)d_out;
  float* ws = (float*)d_ws;

  _Float16* xT   = (_Float16*)(ws + oXT);
  _Float16* xH   = (_Float16*)(ws + oXH);
  float* Spart   = ws + oSpart;
  float* S       = ws + oS;
  float* Gp      = ws + oGp;
  float* sums    = ws + oSums;
  float* gv      = ws + oGv;
  float* sArr    = ws + oSc;
  float* tArr    = ws + oTc;
  float* score   = ws + oScore;
  float* P       = ws + oP;
  float* Aq      = ws + oAq;
  float* M       = ws + oM;
  _Float16* GmH  = (_Float16*)(ws + oGmH);

  // sums + gvec are adjacent: one memset covers both
  hipMemsetAsync(sums, 0, (size_t)2 * kB * kC * sizeof(float), stream);
  k0_tr<<<dim3(kHW / 64, kC / 64, kB), 256, 0, stream>>>(x, xT, xH, sums);
  k1_syrk<<<dim3(3 * kNSplit, kB), 256, 0, stream>>>(xH, Spart);
  k1r_reduce<<<dim3(3 * kB * kNSplit), 256, 0, stream>>>(Spart, S);
  k2a_stats<<<kB, 256, 0, stream>>>(S, sums, gnw, gnb, sArr, tArr);
  k2_fold<<<dim3(kCP1, kB), 256, 0, stream>>>(S, sums, sArr, tArr, Gp);
  k3a_aq<<<dim3(5, 4, kB), 256, 0, stream>>>(Gp, qkvw, qkvb, Aq);
  k3b_scores<<<dim3(kHeads, kB), 256, 0, stream>>>(Aq, qkvw, qkvb, score);
  k4_softmax<<<dim3(16, kB), 64, 0, stream>>>(score, P);
  k5a_M<<<dim3(kC, kB), 256, 0, stream>>>(P, qkvw, qkvb, M);
  k5b_gemm<<<dim3(5, 4, kB), 256, 0, stream>>>(M, outw, sArr, tArr, GmH, gv);
  k6_final<<<dim3(kHW / 128, kC / 128, kB), 256, 0, stream>>>(xT, GmH, gv, outb, x, out);
}

// Round 4
// 238.858 us; speedup vs baseline: 2.4241x; 1.0587x over previous
//
#include <hip/hip_runtime.h>

// ---------------------------------------------------------------------------
// Algebraic collapse + fp16 MFMA (rounds 1-3) + round-4:
//   - kNSplit 32 (384 k1 blocks, full CU coverage)
//   - k1r writes full-symmetric padded S; k2_fold folded INTO k3a staging
//   - k4 softmax merged into k5a (k45_M)
//   - k6 epilogue: LDS-staged coalesced float4 stores + float4 skip loads
// ---------------------------------------------------------------------------

constexpr int kB = 4;
constexpr int kC = 256;
constexpr int kHW = 16384;
constexpr int kHeads = 64;
constexpr int kNG = 32;
constexpr int kCPG = 8;
constexpr int kCP1 = 257;
constexpr int kPS = 260;          // padded row stride (floats) for S / M
constexpr float kEPS = 1e-5f;
constexpr int kNSplit = 32;       // syrk K-splits

typedef __attribute__((ext_vector_type(8))) _Float16 f16x8;
typedef __attribute__((ext_vector_type(4))) _Float16 f16x4;
typedef __attribute__((ext_vector_type(4))) float f32x4;

union V8 { f16x8 v; uint4 u; _Float16 h[8]; };

// workspace layout (float-unit offsets)
constexpr size_t oXT    = 0;                                    // fp16 xT [b][n][c]
constexpr size_t oXH    = oXT + (size_t)kB * kHW * kC / 2;      // fp16 xH [b][c][n]
constexpr size_t oSpart = oXH + (size_t)kB * kHW * kC / 2;      // 3*B*kNSplit*128*128
constexpr size_t oS     = oSpart + (size_t)3 * kB * kNSplit * 128 * 128;
constexpr size_t oSums  = oS + (size_t)kB * kCP1 * kPS;         // B x 256 exact row sums
constexpr size_t oGv    = oSums + (size_t)kB * kC;              // adjacent (one memset)
constexpr size_t oSc    = oGv + (size_t)kB * kC;
constexpr size_t oTc    = oSc + (size_t)kB * kC;
constexpr size_t oScore = oTc + (size_t)kB * kC;
// overlays (lifetime-disjoint):
constexpr size_t oAq    = oSpart;                               // B x 256 x 257 (after k1r)
constexpr size_t oM     = oXH;                                  // B x 256 x 260 (after k1)
constexpr size_t oGmH   = oXH + (size_t)kB * kC * kPS;          // fp16 B x 256 x 256

// ---------------------------------------------------------------------------
// K0: tiled transpose x -> xT (fp16) + xH (fp16 [b][c][n]) + fp32 row sums.
// grid (HW/64, C/64, B), 256 thr.
// ---------------------------------------------------------------------------
__global__ __launch_bounds__(256) void k0_tr(const float* __restrict__ x,
                                             _Float16* __restrict__ xT,
                                             _Float16* __restrict__ xH,
                                             float* __restrict__ sums) {
  const int nt = blockIdx.x, ct = blockIdx.y, b = blockIdx.z;
  __shared__ float T[64][65];
  __shared__ float psum[64][4];
  const float* xb = x + ((size_t)b * kC + ct * 64) * kHW + nt * 64;
  _Float16* xhb = xH + ((size_t)b * kC + ct * 64) * kHW + nt * 64;
  const int tid = threadIdx.x;

#pragma unroll
  for (int rep = 0; rep < 4; ++rep) {
    const int r = rep * 16 + (tid >> 4);          // c-local
    const int c4 = (tid & 15) * 4;                // n-local
    float4 v = *(const float4*)(xb + (size_t)r * kHW + c4);
    T[r][c4 + 0] = v.x; T[r][c4 + 1] = v.y; T[r][c4 + 2] = v.z; T[r][c4 + 3] = v.w;
    f16x4 hv = {(_Float16)v.x, (_Float16)v.y, (_Float16)v.z, (_Float16)v.w};
    *(f16x4*)(xhb + (size_t)r * kHW + c4) = hv;
  }
  __syncthreads();
  {
    const int q = tid >> 6, r = tid & 63;
    float s = 0.f;
#pragma unroll
    for (int i = 0; i < 16; ++i) s += T[r][q * 16 + i];
    psum[r][q] = s;
  }
  __syncthreads();
  if (tid < 64) {
    float s = psum[tid][0] + psum[tid][1] + psum[tid][2] + psum[tid][3];
    atomicAdd(&sums[b * kC + ct * 64 + tid], s);
  }
  const int nl = tid >> 2, cgrp = tid & 3;
  V8 lo, hi;
#pragma unroll
  for (int i = 0; i < 8; ++i)  lo.h[i] = (_Float16)T[cgrp * 16 + i][nl];
#pragma unroll
  for (int i = 0; i < 8; ++i)  hi.h[i] = (_Float16)T[cgrp * 16 + 8 + i][nl];
  _Float16* dst = xT + ((size_t)b * kHW + nt * 64 + nl) * kC + ct * 64 + cgrp * 16;
  *(uint4*)dst = lo.u;
  *(uint4*)(dst + 8) = hi.u;
}

// ---------------------------------------------------------------------------
// K1: MFMA syrk reading xH. Tiles (0,0),(0,1),(1,1) of 128x128; 32 K-splits.
// grid (3*32, B), 256 thr. LDS swizzle g^(r&7).
// ---------------------------------------------------------------------------
__global__ __launch_bounds__(256) void k1_syrk(const _Float16* __restrict__ xH,
                                               float* __restrict__ Spart) {
  const int tt = blockIdx.x >> 5;   // /kNSplit
  const int sp = blockIdx.x & 31;
  const int b = blockIdx.y;
  const int ti = (tt == 2) ? 1 : 0;
  const int tj = (tt == 0) ? 0 : 1;
  const bool diag = (ti == tj);
  const _Float16* xb = xH + (size_t)b * kC * kHW;
  const int n0 = sp * (kHW / kNSplit);   // 512 per split

  __shared__ __align__(16) _Float16 XI[128 * 64];
  __shared__ __align__(16) _Float16 XJ[128 * 64];

  const int tid = threadIdx.x;
  const int wave = tid >> 6, lane = tid & 63;
  const int wi = wave >> 1, wj = wave & 1;
  const int lrow = lane & 15, lgq = lane >> 4;

  f32x4 acc[16];
#pragma unroll
  for (int i = 0; i < 16; ++i) acc[i] = (f32x4){0.f, 0.f, 0.f, 0.f};

  for (int ch = 0; ch < kHW / kNSplit / 64; ++ch) {
    const int nb = n0 + ch * 64;
#pragma unroll
    for (int rep = 0; rep < 4; ++rep) {
      const int gi = tid + rep * 256;
      const int r = gi >> 3, g = gi & 7;
      const size_t boff = (size_t)r * 128 + (((unsigned)(g ^ (r & 7))) << 4);
      uint4 va = *(const uint4*)(xb + (size_t)(ti * 128 + r) * kHW + nb + g * 8);
      *(uint4*)((char*)XI + boff) = va;
      if (!diag) {
        uint4 vb = *(const uint4*)(xb + (size_t)(tj * 128 + r) * kHW + nb + g * 8);
        *(uint4*)((char*)XJ + boff) = vb;
      }
    }
    __syncthreads();
    const _Float16* XB = diag ? XI : XJ;
#pragma unroll
    for (int sub = 0; sub < 2; ++sub) {
      const int gq = sub * 4 + lgq;
      f16x8 afr[4], bfr[4];
#pragma unroll
      for (int ia = 0; ia < 4; ++ia) {
        const int r = wi * 64 + ia * 16 + lrow;
        afr[ia] = *(const f16x8*)((const char*)XI + (size_t)r * 128 + (((unsigned)(gq ^ (r & 7))) << 4));
      }
#pragma unroll
      for (int jb = 0; jb < 4; ++jb) {
        const int r = wj * 64 + jb * 16 + lrow;
        bfr[jb] = *(const f16x8*)((const char*)XB + (size_t)r * 128 + (((unsigned)(gq ^ (r & 7))) << 4));
      }
#pragma unroll
      for (int ia = 0; ia < 4; ++ia)
#pragma unroll
        for (int jb = 0; jb < 4; ++jb)
          acc[ia * 4 + jb] = __builtin_amdgcn_mfma_f32_16x16x32_f16(afr[ia], bfr[jb], acc[ia * 4 + jb], 0, 0, 0);
    }
    __syncthreads();
  }
  float* P = Spart + (((size_t)tt * kB + b) * kNSplit + sp) * 16384;
#pragma unroll
  for (int ia = 0; ia < 4; ++ia)
#pragma unroll
    for (int jb = 0; jb < 4; ++jb)
#pragma unroll
      for (int reg = 0; reg < 4; ++reg) {
        const int i = wi * 64 + ia * 16 + lgq * 4 + reg;
        const int j = wj * 64 + jb * 16 + lrow;
        P[(size_t)i * 128 + j] = acc[ia * 4 + jb][reg];
      }
}

// ---------------------------------------------------------------------------
// K1r: reduce split partials -> full symmetric padded S (stride kPS).
// grid (3*B*16), 256 thr, 4 elems each, loop over 32 splits.
// ---------------------------------------------------------------------------
__global__ __launch_bounds__(256) void k1r_reduce(const float* __restrict__ Spart,
                                                  float* __restrict__ S) {
  const int blk = blockIdx.x;
  const int tile12 = blk >> 4;          // 0..11
  const int part = blk & 15;
  const int tt = tile12 >> 2, b = tile12 & 3;
  const int rti = (tt == 2) ? 1 : 0;
  const int rtj = (tt == 0) ? 0 : 1;
  const int e0 = part * 1024 + threadIdx.x * 4;
  float4 s = {0.f, 0.f, 0.f, 0.f};
  const float* base = Spart + ((size_t)tt * kB + b) * kNSplit * 16384 + e0;
  for (int sp = 0; sp < kNSplit; ++sp) {
    float4 v = *(const float4*)(base + (size_t)sp * 16384);
    s.x += v.x; s.y += v.y; s.z += v.z; s.w += v.w;
  }
  const int i = e0 >> 7, j = e0 & 127;
  float* Sb = S + (size_t)b * kCP1 * kPS;
  float* dst = Sb + (size_t)(rti * 128 + i) * kPS + rtj * 128 + j;
  dst[0] = s.x; dst[1] = s.y; dst[2] = s.z; dst[3] = s.w;
  if (tt == 1) {  // mirror into lower triangle
    Sb[(size_t)(128 + j + 0) * kPS + i] = s.x;
    Sb[(size_t)(128 + j + 1) * kPS + i] = s.y;
    Sb[(size_t)(128 + j + 2) * kPS + i] = s.z;
    Sb[(size_t)(128 + j + 3) * kPS + i] = s.w;
  }
}

// ---------------------------------------------------------------------------
// K2a: GN stats from padded-S diag + exact sums -> affine (s_c, t_c).
// ---------------------------------------------------------------------------
__global__ __launch_bounds__(256) void k2a_stats(const float* __restrict__ S,
                                                 const float* __restrict__ sums,
                                                 const float* __restrict__ gw,
                                                 const float* __restrict__ gb,
                                                 float* __restrict__ sArr,
                                                 float* __restrict__ tArr) {
  const int b = blockIdx.x;
  const float* Sb = S + (size_t)b * kCP1 * kPS;
  __shared__ float sx[kC], sdg[kC], meanv[kNG], invv[kNG];
  const int c = threadIdx.x;
  sx[c]  = sums[b * kC + c];
  sdg[c] = Sb[(size_t)c * kPS + c];
  __syncthreads();
  if (c < kNG) {
    float sum = 0.f, ssq = 0.f;
    for (int k = 0; k < kCPG; ++k) { sum += sx[c * kCPG + k]; ssq += sdg[c * kCPG + k]; }
    const float n = (float)(kCPG * kHW);
    const float mean = sum / n;
    const float var = (ssq - n * mean * mean) / (n - 1.0f);  // ddof=1
    meanv[c] = mean;
    invv[c] = rsqrtf(var + kEPS);
  }
  __syncthreads();
  const int g = c / kCPG;
  const float s = gw[c] * invv[g];
  sArr[b * kC + c] = s;
  tArr[b * kC + c] = gb[c] - meanv[g] * s;
}

// ---------------------------------------------------------------------------
// K3a: Aq[b,m,cp] = sum_c Wq'[m,c] * Gram'[c,cp], Gram' folded INLINE from
// raw S: Gram'[r,c] = s_r*(s_c*S[r,c] + t_c*Sx_r) + t_r*r256[c], where
// r256[c] = s_c*Sx_c + t_c*HW. grid (5 cp-tiles, 4 m-tiles, B), 256 thr.
// ---------------------------------------------------------------------------
__global__ __launch_bounds__(256) void k3a_aq(const float* __restrict__ S,
                                              const float* __restrict__ sums,
                                              const float* __restrict__ sArr,
                                              const float* __restrict__ tArr,
                                              const float* __restrict__ qkv_w,
                                              const float* __restrict__ qkv_b,
                                              float* __restrict__ Aq) {
  const int ct = blockIdx.x, mt = blockIdx.y, b = blockIdx.z;
  const float* Sb = S + (size_t)b * kCP1 * kPS;
  const float HWf = (float)kHW;
  __shared__ float Wt[32][68];
  __shared__ float Gs[32][68];
  __shared__ float shs[kC], sht[kC], shx[kC], shr[kC];
  const int tid = threadIdx.x;
  {
    const float sv = sArr[b * kC + tid];
    const float tv = tArr[b * kC + tid];
    const float xv = sums[b * kC + tid];
    shs[tid] = sv; sht[tid] = tv; shx[tid] = xv;
    shr[tid] = sv * xv + tv * HWf;
  }
  __syncthreads();
  float acc[16];
#pragma unroll
  for (int i = 0; i < 16; ++i) acc[i] = 0.f;
  const int i0 = (tid & 15) * 4;   // m-local
  const int j0 = (tid >> 4) * 4;   // cp-local
  const int cp0 = ct * 64;

  for (int cb = 0; cb < kC; cb += 32) {
    int idx = tid;
#pragma unroll
    for (int r = 0; r < 2; ++r) {
      const int m = idx >> 3;
      const int c4 = (idx & 7) * 4;
      const int mg = mt * 64 + m;
      const int row = 12 * (mg >> 2) + (mg & 3);
      float4 v = *(const float4*)(qkv_w + (size_t)row * kC + cb + c4);
      Wt[c4 + 0][m] = v.x; Wt[c4 + 1][m] = v.y; Wt[c4 + 2][m] = v.z; Wt[c4 + 3][m] = v.w;
      idx += 256;
    }
    idx = tid;
#pragma unroll
    for (int r = 0; r < 2; ++r) {
      const int cc = idx >> 4;
      const int n4 = (idx & 15) * 4;
      const int rr = cb + cc;
      const float s_r = shs[rr], t_r = sht[rr], x_r = shx[rr];
      float4 o;
      if (cp0 + n4 < kC) {
        float4 v = *(const float4*)(Sb + (size_t)rr * kPS + cp0 + n4);
        const int cp = cp0 + n4;
        o.x = s_r * (shs[cp + 0] * v.x + sht[cp + 0] * x_r) + t_r * shr[cp + 0];
        o.y = s_r * (shs[cp + 1] * v.y + sht[cp + 1] * x_r) + t_r * shr[cp + 1];
        o.z = s_r * (shs[cp + 2] * v.z + sht[cp + 2] * x_r) + t_r * shr[cp + 2];
        o.w = s_r * (shs[cp + 3] * v.w + sht[cp + 3] * x_r) + t_r * shr[cp + 3];
      } else if (cp0 + n4 == kC) {      // augmented column 256
        o = (float4){s_r * x_r + t_r * HWf, 0.f, 0.f, 0.f};
      } else {
        o = (float4){0.f, 0.f, 0.f, 0.f};
      }
      *(float4*)&Gs[cc][n4] = o;
      idx += 256;
    }
    __syncthreads();
#pragma unroll
    for (int kk = 0; kk < 32; ++kk) {
      float4 a = *(const float4*)&Wt[kk][i0];
      float4 g = *(const float4*)&Gs[kk][j0];
      acc[0]  += a.x * g.x; acc[1]  += a.x * g.y; acc[2]  += a.x * g.z; acc[3]  += a.x * g.w;
      acc[4]  += a.y * g.x; acc[5]  += a.y * g.y; acc[6]  += a.y * g.z; acc[7]  += a.y * g.w;
      acc[8]  += a.z * g.x; acc[9]  += a.z * g.y; acc[10] += a.z * g.z; acc[11] += a.z * g.w;
      acc[12] += a.w * g.x; acc[13] += a.w * g.y; acc[14] += a.w * g.z; acc[15] += a.w * g.w;
    }
    __syncthreads();
  }
#pragma unroll
  for (int mi = 0; mi < 4; ++mi) {
    const int mg = mt * 64 + i0 + mi;
    const float bias = qkv_b[12 * (mg >> 2) + (mg & 3)];
#pragma unroll
    for (int cj = 0; cj < 4; ++cj) {
      const int cp = cp0 + j0 + cj;
      if (cp < kCP1) {
        const float g256 = (cp < kC) ? shr[cp] : HWf;   // Gram'[256][cp]
        Aq[((size_t)b * kC + mg) * kCP1 + cp] = acc[mi * 4 + cj] + bias * g256;
      }
    }
  }
}

// ---------------------------------------------------------------------------
// K3b: scores[b,h,d,e] = 0.5 * sum_cp Aq[b,4h+d,cp] * Wk'[4h+e,cp].
// grid (64 heads, B), 256 thr, wave-reduce.
// ---------------------------------------------------------------------------
__global__ __launch_bounds__(256) void k3b_scores(const float* __restrict__ Aq,
                                                  const float* __restrict__ qkv_w,
                                                  const float* __restrict__ qkv_b,
                                                  float* __restrict__ score) {
  const int h = blockIdx.x, b = blockIdx.y;
  const int tid = threadIdx.x, wave = tid >> 6, lane = tid & 63;
#pragma unroll
  for (int p = wave; p < 16; p += 4) {
    const int d = p >> 2, e = p & 3;
    const float* aqr = Aq + ((size_t)b * kC + h * 4 + d) * kCP1;
    const int krow = h * 12 + 4 + e;
    float s = 0.f;
#pragma unroll
    for (int it = 0; it < 4; ++it) {
      const int cp = lane + it * 64;
      s += aqr[cp] * qkv_w[(size_t)krow * kC + cp];
    }
    if (lane == 0) s += aqr[256] * qkv_b[krow];
#pragma unroll
    for (int off = 32; off; off >>= 1) s += __shfl_xor(s, off);
    if (lane == 0) score[((size_t)(b * kHeads) + h) * 16 + p] = 0.5f * s;
  }
}

// ---------------------------------------------------------------------------
// K45: softmax over HEADS (inline, from raw scores) + M = P-mix of Wv'.
// grid (256, B), 256 thr.
// ---------------------------------------------------------------------------
__global__ __launch_bounds__(256) void k45_M(const float* __restrict__ score,
                                             const float* __restrict__ qkv_w,
                                             const float* __restrict__ qkv_b,
                                             float* __restrict__ M) {
  const int b = blockIdx.y;
  const int cidx = blockIdx.x;
  const int h = cidx >> 2, d = cidx & 3;
  __shared__ float sc[64][4];
  __shared__ float mx[4], sm[4];
  const int tid = threadIdx.x;
  {
    const int h2 = tid >> 2, e = tid & 3;
    sc[h2][e] = score[((size_t)(b * kHeads) + h2) * 16 + d * 4 + e];
  }
  __syncthreads();
  const int wave = tid >> 6, lane = tid & 63;
  {
    const float v = sc[lane][wave];
    float m = v;
#pragma unroll
    for (int off = 32; off; off >>= 1) m = fmaxf(m, __shfl_xor(m, off));
    float e2 = expf(v - m);
#pragma unroll
    for (int off = 32; off; off >>= 1) e2 += __shfl_xor(e2, off);
    if (lane == 0) { mx[wave] = m; sm[wave] = e2; }
  }
  __syncthreads();
  const float p0 = expf(sc[h][0] - mx[0]) / sm[0];
  const float p1 = expf(sc[h][1] - mx[1]) / sm[1];
  const float p2 = expf(sc[h][2] - mx[2]) / sm[2];
  const float p3 = expf(sc[h][3] - mx[3]) / sm[3];
  for (int cp = tid; cp < kCP1; cp += 256) {
    float a;
    if (cp < kC) {
      a = p0 * qkv_w[(size_t)(h * 12 + 8 + 0) * kC + cp] +
          p1 * qkv_w[(size_t)(h * 12 + 8 + 1) * kC + cp] +
          p2 * qkv_w[(size_t)(h * 12 + 8 + 2) * kC + cp] +
          p3 * qkv_w[(size_t)(h * 12 + 8 + 3) * kC + cp];
    } else {
      a = p0 * qkv_b[h * 12 + 8 + 0] + p1 * qkv_b[h * 12 + 8 + 1] +
          p2 * qkv_b[h * 12 + 8 + 2] + p3 * qkv_b[h * 12 + 8 + 3];
    }
    M[((size_t)b * kC + cidx) * kPS + cp] = a;
  }
}

// ---------------------------------------------------------------------------
// K5b: F = out_w @ M (tiled 64x64, K=256); emit G fp16 + gvec atomics.
// grid (5 cp-tiles, 4 o-tiles, B), 256 thr.
// ---------------------------------------------------------------------------
__global__ __launch_bounds__(256) void k5b_gemm(const float* __restrict__ M,
                                                const float* __restrict__ out_w,
                                                const float* __restrict__ sArr,
                                                const float* __restrict__ tArr,
                                                _Float16* __restrict__ GmH,
                                                float* __restrict__ gvec) {
  const int ct = blockIdx.x, ot = blockIdx.y, b = blockIdx.z;
  const float* Mb = M + (size_t)b * kC * kPS;
  __shared__ float Wt[32][68];
  __shared__ float Gs[32][68];
  __shared__ float gred[64][17];
  float acc[16];
#pragma unroll
  for (int i = 0; i < 16; ++i) acc[i] = 0.f;
  const int tid = threadIdx.x;
  const int i0 = (tid & 15) * 4;
  const int j0 = (tid >> 4) * 4;
  const int cp0 = ct * 64;

  for (int cb = 0; cb < kC; cb += 32) {
    int idx = tid;
#pragma unroll
    for (int r = 0; r < 2; ++r) {
      const int m = idx >> 3;
      const int c4 = (idx & 7) * 4;
      float4 v = *(const float4*)(out_w + (size_t)(ot * 64 + m) * kC + cb + c4);
      Wt[c4 + 0][m] = v.x; Wt[c4 + 1][m] = v.y; Wt[c4 + 2][m] = v.z; Wt[c4 + 3][m] = v.w;
      idx += 256;
    }
    idx = tid;
#pragma unroll
    for (int r = 0; r < 2; ++r) {
      const int cc = idx >> 4;
      const int n4 = (idx & 15) * 4;
      float4 v = {0.f, 0.f, 0.f, 0.f};
      if (cp0 + n4 < kCP1) v = *(const float4*)(Mb + (size_t)(cb + cc) * kPS + cp0 + n4);
      *(float4*)&Gs[cc][n4] = v;
      idx += 256;
    }
    __syncthreads();
#pragma unroll
    for (int kk = 0; kk < 32; ++kk) {
      float4 a = *(const float4*)&Wt[kk][i0];
      float4 g = *(const float4*)&Gs[kk][j0];
      acc[0]  += a.x * g.x; acc[1]  += a.x * g.y; acc[2]  += a.x * g.z; acc[3]  += a.x * g.w;
      acc[4]  += a.y * g.x; acc[5]  += a.y * g.y; acc[6]  += a.y * g.z; acc[7]  += a.y * g.w;
      acc[8]  += a.z * g.x; acc[9]  += a.z * g.y; acc[10] += a.z * g.z; acc[11] += a.z * g.w;
      acc[12] += a.w * g.x; acc[13] += a.w * g.y; acc[14] += a.w * g.z; acc[15] += a.w * g.w;
    }
    __syncthreads();
  }
  float gpart[4] = {0.f, 0.f, 0.f, 0.f};
#pragma unroll
  for (int mi = 0; mi < 4; ++mi) {
    const int o = ot * 64 + i0 + mi;
#pragma unroll
    for (int cj = 0; cj < 4; ++cj) {
      const int cp = cp0 + j0 + cj;
      const float f = acc[mi * 4 + cj];
      if (cp < kC) {
        GmH[((size_t)b * kC + o) * kC + cp] = (_Float16)(f * sArr[b * kC + cp]);
        gpart[mi] += f * tArr[b * kC + cp];
      } else if (cp == kC) {
        gpart[mi] += f;
      }
    }
  }
#pragma unroll
  for (int mi = 0; mi < 4; ++mi) gred[i0 + mi][tid >> 4] = gpart[mi];
  __syncthreads();
  if (tid < 64) {
    float s = 0.f;
#pragma unroll
    for (int k = 0; k < 16; ++k) s += gred[tid][k];
    atomicAdd(&gvec[b * kC + ot * 64 + tid], s);
  }
}

// ---------------------------------------------------------------------------
// K6: out = G @ X + (g + out_b) + skip via MFMA; coalesced LDS epilogue.
// grid (HW/128, C/128, B), 256 thr.
// ---------------------------------------------------------------------------
__global__ __launch_bounds__(256) void k6_final(const _Float16* __restrict__ xT,
                                                const _Float16* __restrict__ GmH,
                                                const float* __restrict__ gvec,
                                                const float* __restrict__ out_b,
                                                const float* __restrict__ x,
                                                float* __restrict__ out) {
  const int nt = blockIdx.x, ot = blockIdx.y, b = blockIdx.z;
  __shared__ __align__(16) char smem[64 * 132 * 4];   // 33792 B; aliased below
  _Float16* GT = (_Float16*)smem;                     // 16 KB
  _Float16* XT = (_Float16*)(smem + 16384);           // 16 KB
  float* Ep = (float*)smem;                           // epilogue 64 x 132 fp32
  const int tid = threadIdx.x;
  const int wave = tid >> 6, lane = tid & 63;
  const int wo = wave >> 1, wn = wave & 1;
  const int lrow = lane & 15, lgq = lane >> 4;

  f32x4 acc[16];
#pragma unroll
  for (int i = 0; i < 16; ++i) acc[i] = (f32x4){0.f, 0.f, 0.f, 0.f};

  for (int cc = 0; cc < kC; cc += 64) {
#pragma unroll
    for (int rep = 0; rep < 4; ++rep) {
      const int gi = tid + rep * 256;
      const int r = gi >> 3, g = gi & 7;
      const size_t boff = (size_t)r * 128 + (((unsigned)(g ^ (r & 7))) << 4);
      uint4 gv = *(const uint4*)(GmH + ((size_t)(b * kC + ot * 128 + r)) * kC + cc + g * 8);
      *(uint4*)((char*)GT + boff) = gv;
      uint4 xv = *(const uint4*)(xT + ((size_t)b * kHW + nt * 128 + r) * kC + cc + g * 8);
      *(uint4*)((char*)XT + boff) = xv;
    }
    __syncthreads();
#pragma unroll
    for (int sub = 0; sub < 2; ++sub) {
      const int gq = sub * 4 + lgq;
      f16x8 afr[4], bfr[4];
#pragma unroll
      for (int ia = 0; ia < 4; ++ia) {
        const int r = wo * 64 + ia * 16 + lrow;
        afr[ia] = *(const f16x8*)((const char*)GT + (size_t)r * 128 + (((unsigned)(gq ^ (r & 7))) << 4));
      }
#pragma unroll
      for (int jb = 0; jb < 4; ++jb) {
        const int r = wn * 64 + jb * 16 + lrow;
        bfr[jb] = *(const f16x8*)((const char*)XT + (size_t)r * 128 + (((unsigned)(gq ^ (r & 7))) << 4));
      }
#pragma unroll
      for (int ia = 0; ia < 4; ++ia)
#pragma unroll
        for (int jb = 0; jb < 4; ++jb)
          acc[ia * 4 + jb] = __builtin_amdgcn_mfma_f32_16x16x32_f16(afr[ia], bfr[jb], acc[ia * 4 + jb], 0, 0, 0);
    }
    __syncthreads();
  }
  // Coalesced epilogue: two o-half passes through LDS.
#pragma unroll
  for (int p = 0; p < 2; ++p) {
    if (wo == p) {
#pragma unroll
      for (int ia = 0; ia < 4; ++ia)
#pragma unroll
        for (int jb = 0; jb < 4; ++jb)
#pragma unroll
          for (int reg = 0; reg < 4; ++reg)
            Ep[(size_t)(ia * 16 + lgq * 4 + reg) * 132 + wn * 64 + jb * 16 + lrow] =
                acc[ia * 4 + jb][reg];
    }
    __syncthreads();
#pragma unroll
    for (int it = 0; it < 8; ++it) {
      const int id = it * 256 + tid;
      const int row = id >> 5, nc = (id & 31) * 4;
      const int o = ot * 128 + p * 64 + row;
      const float gvv = gvec[b * kC + o] + out_b[o];
      float4 e = *(const float4*)&Ep[(size_t)row * 132 + nc];
      const size_t gidx = ((size_t)b * kC + o) * kHW + nt * 128 + nc;
      float4 sk = *(const float4*)&x[gidx];
      float4 res = {e.x + gvv + sk.x, e.y + gvv + sk.y, e.z + gvv + sk.z, e.w + gvv + sk.w};
      *(float4*)&out[gidx] = res;
    }
    __syncthreads();
  }
}

extern "C" void kernel_launch(void* const* d_in, const int* in_sizes, int n_in,
                              void* d_out, int out_size, void* d_ws, size_t ws_size,
                              hipStream_t stream) {
  const float* x    = (const float*)d_in[0];
  const float* gnw  = (const float*)d_in[1];
  const float* gnb  = (const float*)d_in[2];
  const float* qkvw = (const float*)d_in[3];
  const float* qkvb = (const float*)d_in[4];
  const float* outw = (const float*)d_in[5];
  const float* outb = (const float*)d_in[6];
  float* out = (float*)d_out;
  float* ws = (float*)d_ws;

  _Float16* xT   = (_Float16*)(ws + oXT);
  _Float16* xH   = (_Float16*)(ws + oXH);
  float* Spart   = ws + oSpart;
  float* S       = ws + oS;
  float* sums    = ws + oSums;
  float* gv      = ws + oGv;
  float* sArr    = ws + oSc;
  float* tArr    = ws + oTc;
  float* score   = ws + oScore;
  float* Aq      = ws + oAq;
  float* M       = ws + oM;
  _Float16* GmH  = (_Float16*)(ws + oGmH);

  // sums + gvec adjacent: one memset covers both
  hipMemsetAsync(sums, 0, (size_t)2 * kB * kC * sizeof(float), stream);
  k0_tr<<<dim3(kHW / 64, kC / 64, kB), 256, 0, stream>>>(x, xT, xH, sums);
  k1_syrk<<<dim3(3 * kNSplit, kB), 256, 0, stream>>>(xH, Spart);
  k1r_reduce<<<dim3(3 * kB * 16), 256, 0, stream>>>(Spart, S);
  k2a_stats<<<kB, 256, 0, stream>>>(S, sums, gnw, gnb, sArr, tArr);
  k3a_aq<<<dim3(5, 4, kB), 256, 0, stream>>>(S, sums, sArr, tArr, qkvw, qkvb, Aq);
  k3b_scores<<<dim3(kHeads, kB), 256, 0, stream>>>(Aq, qkvw, qkvb, score);
  k45_M<<<dim3(kC, kB), 256, 0, stream>>>(score, qkvw, qkvb, M);
  k5b_gemm<<<dim3(5, 4, kB), 256, 0, stream>>>(M, outw, sArr, tArr, GmH, gv);
  k6_final<<<dim3(kHW / 128, kC / 128, kB), 256, 0, stream>>>(xT, GmH, gv, outb, x, out);
}